// Round 1
// 653.167 us; speedup vs baseline: 1.0202x; 1.0202x over previous
//
#include <hip/hip_runtime.h>
#include <cstdint>

#define TOKENS 4096
#define DMODEL 1024
#define DFF    4096
#define NEXP   8
#define SLOTS  (2 * TOKENS)   // 8192 (token,expert) pairs
#define KS2    2              // K-split for gemm2 (4096 -> 2 x 2048), partial Y buffers
#define MAXT   71             // max total m-tiles: floor(8192/128) + 7

typedef unsigned short u16;
typedef __attribute__((ext_vector_type(8))) short short8;   // 8 bf16 (4 VGPRs)
typedef __attribute__((ext_vector_type(4))) float f32x4;

__device__ __forceinline__ u16 f2bf(float f) {
  union { float f; uint32_t u; } c; c.f = f;
  uint32_t u = c.u;
  u += 0x7fffu + ((u >> 16) & 1u);   // round-to-nearest-even
  return (u16)(u >> 16);
}

__device__ __forceinline__ void gl_lds16(const void* g, void* l) {
  __builtin_amdgcn_global_load_lds((__attribute__((address_space(1))) void*)(g),
                                   (__attribute__((address_space(3))) void*)(l),
                                   16, 0, 0);
}

// ------- W [E][K][N] fp32 -> [E][N][K] bf16 (K-major for MFMA operands) -------
// Fused: z<8 handles W1 expert z, z>=8 handles W2 expert z-8 (same 1024 tiles/expert).
__global__ void transpose_cvt_kernel(const float* __restrict__ W1, u16* __restrict__ w1t,
                                     const float* __restrict__ W2, u16* __restrict__ w2t) {
  const int z = blockIdx.z;
  int K, N; const float* ip; u16* op;
  if (z < 8) { K = DMODEL; N = DFF;    ip = W1 + (size_t)z * K * N;       op = w1t + (size_t)z * K * N; }
  else       { K = DFF;    N = DMODEL; ip = W2 + (size_t)(z - 8) * K * N; op = w2t + (size_t)(z - 8) * K * N; }
  const int ntn = N >> 6;                       // tiles along N (64 or 16, pow2)
  const int nt = (blockIdx.x & (ntn - 1)) << 6;
  const int kt = (blockIdx.x / ntn) << 6;

  __shared__ float tile[64][65];
  const int tid = threadIdx.x;
#pragma unroll
  for (int i = 0; i < 4; i++) {
    int idx = tid + i * 256;          // 1024 = 64 rows x 16 col-groups
    int r = idx >> 4, cg = idx & 15;
    float4 v = *(const float4*)&ip[(size_t)(kt + r) * N + nt + cg * 4];
    tile[r][cg * 4 + 0] = v.x;
    tile[r][cg * 4 + 1] = v.y;
    tile[r][cg * 4 + 2] = v.z;
    tile[r][cg * 4 + 3] = v.w;
  }
  __syncthreads();
#pragma unroll
  for (int i = 0; i < 2; i++) {
    int rr = (tid >> 3) + i * 32;
    int kc = tid & 7;
    union { u16 u[8]; uint4 v; } r8;
#pragma unroll
    for (int j = 0; j < 8; j++) r8.u[j] = f2bf(tile[kc * 8 + j][rr]);
    *(uint4*)&op[(size_t)(nt + rr) * K + kt + kc * 8] = r8.v;
  }
}

// ---------------- gating (+ fused x fp32->bf16): one wave per token ----------------
__global__ void gate_kernel(const float* __restrict__ x, const float* __restrict__ Wg,
                            const float* __restrict__ bg, int* __restrict__ counts,
                            int* __restrict__ slot_tok, float* __restrict__ slot_w,
                            u16* __restrict__ xb) {
  const int t = blockIdx.x;
  const int lane = threadIdx.x;      // 64 lanes
  const float* xr = x + (size_t)t * DMODEL;
  float acc[NEXP];
#pragma unroll
  for (int e = 0; e < NEXP; e++) acc[e] = 0.f;
#pragma unroll
  for (int i = 0; i < 4; i++) {
    int k = (lane + i * 64) * 4;
    float4 xv = *(const float4*)&xr[k];
    // fused conversion: this pass over x also produces the bf16 copy for gemm1
    union { u16 u[4]; uint2 v; } q;
    q.u[0] = f2bf(xv.x); q.u[1] = f2bf(xv.y); q.u[2] = f2bf(xv.z); q.u[3] = f2bf(xv.w);
    *(uint2*)&xb[(size_t)t * DMODEL + k] = q.v;
    const float* wr = &Wg[k * NEXP];
    float xa[4] = {xv.x, xv.y, xv.z, xv.w};
#pragma unroll
    for (int j = 0; j < 4; j++)
#pragma unroll
      for (int e = 0; e < NEXP; e++) acc[e] += xa[j] * wr[j * NEXP + e];
  }
#pragma unroll
  for (int off = 32; off >= 1; off >>= 1)
#pragma unroll
    for (int e = 0; e < NEXP; e++) acc[e] += __shfl_xor(acc[e], off);
  if (lane == 0) {
#pragma unroll
    for (int e = 0; e < NEXP; e++) acc[e] += bg[e];
    int i0 = 0; float v0 = acc[0];
#pragma unroll
    for (int e = 1; e < NEXP; e++) if (acc[e] > v0) { v0 = acc[e]; i0 = e; }
    int i1 = -1; float v1 = -3.0e38f;
#pragma unroll
    for (int e = 0; e < NEXP; e++) if (e != i0 && acc[e] > v1) { v1 = acc[e]; i1 = e; }
    float ex = __expf(v1 - v0);          // v0 >= v1, stable
    float inv = 1.0f / (1.0f + ex);
    int p0 = atomicAdd(&counts[i0], 1);
    slot_tok[i0 * TOKENS + p0] = t * 2;     slot_w[i0 * TOKENS + p0] = inv;
    int p1 = atomicAdd(&counts[i1], 1);
    slot_tok[i1 * TOKENS + p1] = t * 2 + 1; slot_w[i1 * TOKENS + p1] = ex * inv;
  }
}

// prefix over slots AND over m-tiles (compact GEMM work list)
__global__ void prefix_kernel(const int* __restrict__ counts, int* __restrict__ base,
                              int* __restrict__ tstart) {
  if (threadIdx.x == 0) {
    int s = 0, ts = 0;
    for (int e = 0; e < NEXP; e++) {
      base[e] = s; tstart[e] = ts;
      s += counts[e];
      ts += (counts[e] + 127) >> 7;
    }
    tstart[NEXP] = ts;
  }
}

// ---------------- token -> (global slot, weight) inverse map ----------------
__global__ void build_map_kernel(const int* __restrict__ counts, const int* __restrict__ base,
                                 const int* __restrict__ slot_tok, const float* __restrict__ slot_w,
                                 int* __restrict__ tok_map, float* __restrict__ tok_w) {
  int e = blockIdx.y;
  int p = blockIdx.x * 256 + threadIdx.x;
  if (p < counts[e]) {
    int t2 = slot_tok[e * TOKENS + p];   // t*2 + which-of-top2
    tok_map[t2] = base[e] + p;
    tok_w[t2] = slot_w[e * TOKENS + p];
  }
}

// LDS bank-conflict swizzle for the 128x32-u16 staging tiles (64 B rows):
// LDS 16B-chunk (row r, chunk c) holds global chunk (r, c ^ ((r>>1)&3)).
// Staging: gl_lds dest stays LINEAR (HW requirement); the global SOURCE k-offset
// is permuted per thread. Read: same XOR on the ds_read chunk index (involution).
// Effect: a 16-consecutive-row b128 read covers all 8 16B bank-slots (2-way, free)
// instead of 2 slots (8-way).
__device__ __forceinline__ int swz_koff(int c) {           // staging thread c -> u16 offset
  return (((c & 3) ^ ((c >> 3) & 3)) * 8);
}
__device__ __forceinline__ int swz_read(int R, int chunk) { // row R, wanted chunk -> u16 offset
  return R * 32 + ((chunk ^ ((R >> 1) & 3)) * 8);
}

// ---------------- GEMM1: H[slot, :] = relu(Xgather @ W1t^T + b1), bf16 out ----------------
__global__ __launch_bounds__(256, 4) void gemm1_kernel(
    const u16* __restrict__ xb, const u16* __restrict__ w1t, const float* __restrict__ b1,
    const int* __restrict__ slot_tok, const int* __restrict__ counts,
    const int* __restrict__ base, const int* __restrict__ tstart, u16* __restrict__ H) {
  const int nt = blockIdx.x & 31;
  const int trow = blockIdx.x >> 5;
  if (trow >= tstart[NEXP]) return;
  int e = 0;
#pragma unroll
  for (int i = 1; i < NEXP; i++) if (trow >= tstart[i]) e = i;
  const int mt = trow - tstart[e];
  const int cnt = counts[e];
  const int bse = base[e];
  const int tid = threadIdx.x;
  const int lane = tid & 63, wave = tid >> 6;
  const int wm = wave & 1, wn = wave >> 1;

  // 32 KB flat LDS: [As0 | As1 | Bs0 | Bs1], each 128x32 u16 (8 KB).
  // Epilogue reuses the whole 16384-u16 region as a 128x128 bf16 tile.
  __shared__ __align__(16) u16 SM[16384];

  const int c0 = tid, c1 = tid + 256;           // each: row=c>>2, kchunk=c&3
  const int ar0 = mt * 128 + (c0 >> 2), ar1 = mt * 128 + (c1 >> 2);
  const int t0 = (ar0 < cnt) ? (slot_tok[e * TOKENS + ar0] >> 1) : 0;
  const int t1 = (ar1 < cnt) ? (slot_tok[e * TOKENS + ar1] >> 1) : 0;
  const u16* ag0 = xb + (size_t)t0 * DMODEL + swz_koff(c0);
  const u16* ag1 = xb + (size_t)t1 * DMODEL + swz_koff(c1);
  const u16* wb  = w1t + (size_t)e * DFF * DMODEL;
  const u16* bg0 = wb + (size_t)(nt * 128 + (c0 >> 2)) * DMODEL + swz_koff(c0);
  const u16* bg1 = wb + (size_t)(nt * 128 + (c1 >> 2)) * DMODEL + swz_koff(c1);

  f32x4 acc[4][4] = {};
  const int mr = wm * 64 + (lane & 15);
  const int nr = wn * 64 + (lane & 15);
  const int ch = lane >> 4;                     // wanted 16B k-chunk
  const int NIT = DMODEL / 32;

  // per-lane swizzled read offsets (loop-invariant; only s*4096 varies)
  int offA[4], offB[4];
#pragma unroll
  for (int i = 0; i < 4; i++) {
    offA[i] = swz_read(mr + i * 16, ch);
    offB[i] = 8192 + swz_read(nr + i * 16, ch);
  }

  // prologue: stage iter 0 into buffer 0
  gl_lds16(ag0, &SM[c0 * 8]);
  gl_lds16(ag1, &SM[c1 * 8]);
  gl_lds16(bg0, &SM[8192 + c0 * 8]);
  gl_lds16(bg1, &SM[8192 + c1 * 8]);

  int s = 0;
  for (int it = 0; it < NIT; ++it, s ^= 1) {
    __syncthreads();                 // drains prefetch issued one compute-phase ago
    if (it + 1 < NIT) {
      int k1 = (it + 1) * 32;
      gl_lds16(ag0 + k1, &SM[(s ^ 1) * 4096 + c0 * 8]);
      gl_lds16(ag1 + k1, &SM[(s ^ 1) * 4096 + c1 * 8]);
      gl_lds16(bg0 + k1, &SM[8192 + (s ^ 1) * 4096 + c0 * 8]);
      gl_lds16(bg1 + k1, &SM[8192 + (s ^ 1) * 4096 + c1 * 8]);
    }
    short8 af[4], bf[4];
#pragma unroll
    for (int i = 0; i < 4; i++) af[i] = *(const short8*)&SM[s * 4096 + offA[i]];
#pragma unroll
    for (int i = 0; i < 4; i++) bf[i] = *(const short8*)&SM[s * 4096 + offB[i]];
#pragma unroll
    for (int mi = 0; mi < 4; mi++)
#pragma unroll
      for (int ni = 0; ni < 4; ni++)
        acc[mi][ni] = __builtin_amdgcn_mfma_f32_16x16x32_bf16(af[mi], bf[ni], acc[mi][ni], 0, 0, 0);
  }

  // ---- epilogue: bias+relu+cvt into LDS tile, then coalesced b128 stores ----
  __syncthreads();   // all K-loop LDS reads done before overwrite
  const int rq = (lane >> 4) * 4;
#pragma unroll
  for (int ni = 0; ni < 4; ni++) {
    const int col = wn * 64 + ni * 16 + (lane & 15);
    const float bv = b1[e * DFF + nt * 128 + col];
#pragma unroll
    for (int mi = 0; mi < 4; mi++)
#pragma unroll
      for (int r = 0; r < 4; r++) {
        int row = wm * 64 + mi * 16 + rq + r;
        float v = acc[mi][ni][r] + bv;
        SM[row * 128 + col] = f2bf(v > 0.f ? v : 0.f);
      }
  }
  __syncthreads();
#pragma unroll
  for (int rep = 0; rep < 8; rep++) {
    int idx = rep * 256 + tid;          // 2048 = 128 rows x 16 chunks
    int r = idx >> 4, chk = idx & 15;
    int grow = mt * 128 + r;
    if (grow < cnt)
      *(uint4*)&H[(size_t)(bse + grow) * DFF + nt * 128 + chk * 8] =
          *(const uint4*)&SM[r * 128 + chk * 8];
  }
}

// ------- GEMM2 (K-split x2, no atomics): Yp[ks][slot, :] = H @ W2t^T (+ b2 on ks=0) -------
__global__ __launch_bounds__(256, 4) void gemm2_kernel(
    const u16* __restrict__ H, const u16* __restrict__ w2t, const float* __restrict__ b2,
    const int* __restrict__ counts, const int* __restrict__ base,
    const int* __restrict__ tstart, float* __restrict__ Yp) {
  const int nks = blockIdx.x & 15;
  const int nt = nks & 7, ks = nks >> 3;
  const int trow = blockIdx.x >> 4;
  if (trow >= tstart[NEXP]) return;
  int e = 0;
#pragma unroll
  for (int i = 1; i < NEXP; i++) if (trow >= tstart[i]) e = i;
  const int mt = trow - tstart[e];
  const int cnt = counts[e];
  const int bse = base[e];
  const int kbeg = ks * (DFF / KS2);
  const int tid = threadIdx.x;
  const int lane = tid & 63, wave = tid >> 6;
  const int wm = wave & 1, wn = wave >> 1;

  __shared__ __align__(16) u16 As[2][128 * 32];
  __shared__ __align__(16) u16 Bs[2][128 * 32];

  const int c0 = tid, c1 = tid + 256;
  const int ar0 = mt * 128 + (c0 >> 2), ar1 = mt * 128 + (c1 >> 2);
  const int hr0 = bse + ((ar0 < cnt) ? ar0 : 0);
  const int hr1 = bse + ((ar1 < cnt) ? ar1 : 0);
  const u16* ag0 = H + (size_t)hr0 * DFF + kbeg + swz_koff(c0);
  const u16* ag1 = H + (size_t)hr1 * DFF + kbeg + swz_koff(c1);
  const u16* wb  = w2t + (size_t)e * DMODEL * DFF;
  const u16* bg0 = wb + (size_t)(nt * 128 + (c0 >> 2)) * DFF + kbeg + swz_koff(c0);
  const u16* bg1 = wb + (size_t)(nt * 128 + (c1 >> 2)) * DFF + kbeg + swz_koff(c1);

  f32x4 acc[4][4] = {};
  const int mr = wm * 64 + (lane & 15);
  const int nr = wn * 64 + (lane & 15);
  const int ch = lane >> 4;
  const int NIT = (DFF / KS2) / 32;

  int offA[4], offB[4];
#pragma unroll
  for (int i = 0; i < 4; i++) {
    offA[i] = swz_read(mr + i * 16, ch);
    offB[i] = swz_read(nr + i * 16, ch);
  }

  gl_lds16(ag0, &As[0][c0 * 8]);
  gl_lds16(ag1, &As[0][c1 * 8]);
  gl_lds16(bg0, &Bs[0][c0 * 8]);
  gl_lds16(bg1, &Bs[0][c1 * 8]);

  int s = 0;
  for (int it = 0; it < NIT; ++it, s ^= 1) {
    __syncthreads();
    if (it + 1 < NIT) {
      int k1 = (it + 1) * 32;
      gl_lds16(ag0 + k1, &As[s ^ 1][c0 * 8]);
      gl_lds16(ag1 + k1, &As[s ^ 1][c1 * 8]);
      gl_lds16(bg0 + k1, &Bs[s ^ 1][c0 * 8]);
      gl_lds16(bg1 + k1, &Bs[s ^ 1][c1 * 8]);
    }
    short8 af[4], bf[4];
#pragma unroll
    for (int i = 0; i < 4; i++) af[i] = *(const short8*)&As[s][offA[i]];
#pragma unroll
    for (int i = 0; i < 4; i++) bf[i] = *(const short8*)&Bs[s][offB[i]];
#pragma unroll
    for (int mi = 0; mi < 4; mi++)
#pragma unroll
      for (int ni = 0; ni < 4; ni++)
        acc[mi][ni] = __builtin_amdgcn_mfma_f32_16x16x32_bf16(af[mi], bf[ni], acc[mi][ni], 0, 0, 0);
  }

  // ---- epilogue: repack through LDS (As region, 32x128 fp32 = 16 KB) so global
  // stores are row-contiguous float4 instead of 16 scalar dwords/thread ----
  __syncthreads();     // all K-loop LDS reads done before As is reused
  float* FB = (float*)&As[0][0];
  float* yb = Yp + (size_t)ks * SLOTS * DMODEL;
  float bv[4];
#pragma unroll
  for (int ni = 0; ni < 4; ni++)
    bv[ni] = (ks == 0) ? b2[e * DMODEL + nt * 128 + wn * 64 + ni * 16 + (lane & 15)] : 0.f;
  const int rq = (lane >> 4) * 4;
#pragma unroll
  for (int mi = 0; mi < 4; mi++) {
#pragma unroll
    for (int ni = 0; ni < 4; ni++)
#pragma unroll
      for (int r = 0; r < 4; r++)
        FB[(wm * 16 + rq + r) * 128 + wn * 64 + ni * 16 + (lane & 15)] = acc[mi][ni][r] + bv[ni];
    __syncthreads();
#pragma unroll
    for (int j = 0; j < 4; j++) {
      int fid = j * 256 + tid;               // 1024 float4 = 32 rows x 128 floats
      int lr = fid >> 5, c4 = fid & 31;
      int grow = mt * 128 + (lr >> 4) * 64 + mi * 16 + (lr & 15);
      if (grow < cnt)
        *(float4*)&yb[(size_t)(bse + grow) * DMODEL + nt * 128 + c4 * 4] =
            *(const float4*)&FB[lr * 128 + c4 * 4];
    }
    __syncthreads();   // before next mi overwrites FB
  }
}

// ---------------- combine: out[t] = w0*(Yp0[s0]+Yp1[s0]) + w1*(Yp0[s1]+Yp1[s1]) ----------------
__global__ void combine_kernel(const float* __restrict__ Yp, const int* __restrict__ tok_map,
                               const float* __restrict__ tok_w, float* __restrict__ out) {
  const int t = blockIdx.x;
  const int s0 = tok_map[2 * t], s1 = tok_map[2 * t + 1];
  const float w0 = tok_w[2 * t], w1 = tok_w[2 * t + 1];
  const int i = threadIdx.x * 4;
  const float* y0a = Yp + (size_t)s0 * DMODEL;
  const float* y0b = y0a + (size_t)SLOTS * DMODEL;
  const float* y1a = Yp + (size_t)s1 * DMODEL;
  const float* y1b = y1a + (size_t)SLOTS * DMODEL;
  float4 a = *(const float4*)&y0a[i];
  float4 b = *(const float4*)&y0b[i];
  float4 c = *(const float4*)&y1a[i];
  float4 d = *(const float4*)&y1b[i];
  float4 r;
  r.x = w0 * (a.x + b.x) + w1 * (c.x + d.x);
  r.y = w0 * (a.y + b.y) + w1 * (c.y + d.y);
  r.z = w0 * (a.z + b.z) + w1 * (c.z + d.z);
  r.w = w0 * (a.w + b.w) + w1 * (c.w + d.w);
  *(float4*)&out[(size_t)t * DMODEL + i] = r;
}

extern "C" void kernel_launch(void* const* d_in, const int* in_sizes, int n_in,
                              void* d_out, int out_size, void* d_ws, size_t ws_size,
                              hipStream_t stream) {
  const float* x  = (const float*)d_in[0];
  const float* Wg = (const float*)d_in[1];
  const float* bg = (const float*)d_in[2];
  const float* W1 = (const float*)d_in[3];
  const float* b1 = (const float*)d_in[4];
  const float* W2 = (const float*)d_in[5];
  const float* b2 = (const float*)d_in[6];
  float* out = (float*)d_out;

  char* p = (char*)d_ws;
  int*   counts   = (int*)p;   p += 256;
  int*   base     = (int*)p;   p += 256;
  int*   tstart   = (int*)p;   p += 256;
  int*   slot_tok = (int*)p;   p += (size_t)NEXP * TOKENS * 4;
  float* slot_w   = (float*)p; p += (size_t)NEXP * TOKENS * 4;
  int*   tok_map  = (int*)p;   p += (size_t)SLOTS * 4;
  float* tok_w    = (float*)p; p += (size_t)SLOTS * 4;
  u16*   xb       = (u16*)p;   p += (size_t)TOKENS * DMODEL * 2;
  u16*   w1t      = (u16*)p;   p += (size_t)NEXP * DMODEL * DFF * 2;   // 64 MB
  u16*   w2t      = (u16*)p;   p += (size_t)NEXP * DMODEL * DFF * 2;   // 64 MB
  u16*   H        = (u16*)p;   p += (size_t)SLOTS * DFF * 2;           // 64 MB
  // Yp (2 x 32 MB fp32 partials) ALIASES w1t: w1t is dead once gemm1 completes,
  // and gemm2 (which writes Yp) is ordered after gemm1 on the stream.
  float* Yp = (float*)w1t;
  // total ws use: ~200.8 MB

  (void)hipMemsetAsync(counts, 0, 256, stream);

  transpose_cvt_kernel<<<dim3(1024, 1, 16), 256, 0, stream>>>(W1, w1t, W2, w2t);
  gate_kernel<<<TOKENS, 64, 0, stream>>>(x, Wg, bg, counts, slot_tok, slot_w, xb);
  prefix_kernel<<<1, 64, 0, stream>>>(counts, base, tstart);
  build_map_kernel<<<dim3(TOKENS / 256, NEXP), 256, 0, stream>>>(
      counts, base, slot_tok, slot_w, tok_map, tok_w);
  gemm1_kernel<<<MAXT * 32, 256, 0, stream>>>(
      xb, w1t, b1, slot_tok, counts, base, tstart, H);
  gemm2_kernel<<<MAXT * 16, 256, 0, stream>>>(
      H, w2t, b2, counts, base, tstart, Yp);
  combine_kernel<<<TOKENS, 256, 0, stream>>>(Yp, tok_map, tok_w, out);
}

// Round 2
// 649.745 us; speedup vs baseline: 1.0255x; 1.0053x over previous
//
#include <hip/hip_runtime.h>
#include <cstdint>

#define TOKENS 4096
#define DMODEL 1024
#define DFF    4096
#define NEXP   8
#define SLOTS  (2 * TOKENS)   // 8192 (token,expert) pairs
#define KS2    2              // K-split for gemm2 (4096 -> 2 x 2048), partial Y buffers
#define MAXT256 39            // max total 256-row m-tiles: floor(8192/256) + 7

typedef unsigned short u16;
typedef __attribute__((ext_vector_type(8))) short short8;   // 8 bf16 (4 VGPRs)
typedef __attribute__((ext_vector_type(4))) float f32x4;

__device__ __forceinline__ u16 f2bf(float f) {
  union { float f; uint32_t u; } c; c.f = f;
  uint32_t u = c.u;
  u += 0x7fffu + ((u >> 16) & 1u);   // round-to-nearest-even
  return (u16)(u >> 16);
}

__device__ __forceinline__ void gl_lds16(const void* g, void* l) {
  __builtin_amdgcn_global_load_lds((__attribute__((address_space(1))) void*)(g),
                                   (__attribute__((address_space(3))) void*)(l),
                                   16, 0, 0);
}

#define CFENCE() asm volatile("" ::: "memory")
#define VMCNT4() asm volatile("s_waitcnt vmcnt(4)" ::: "memory")

// ------- W [E][K][N] fp32 -> [E][N][K] bf16 (K-major for MFMA operands) -------
__global__ void transpose_cvt_kernel(const float* __restrict__ W1, u16* __restrict__ w1t,
                                     const float* __restrict__ W2, u16* __restrict__ w2t) {
  const int z = blockIdx.z;
  int K, N; const float* ip; u16* op;
  if (z < 8) { K = DMODEL; N = DFF;    ip = W1 + (size_t)z * K * N;       op = w1t + (size_t)z * K * N; }
  else       { K = DFF;    N = DMODEL; ip = W2 + (size_t)(z - 8) * K * N; op = w2t + (size_t)(z - 8) * K * N; }
  const int ntn = N >> 6;
  const int nt = (blockIdx.x & (ntn - 1)) << 6;
  const int kt = (blockIdx.x / ntn) << 6;

  __shared__ float tile[64][65];
  const int tid = threadIdx.x;
#pragma unroll
  for (int i = 0; i < 4; i++) {
    int idx = tid + i * 256;
    int r = idx >> 4, cg = idx & 15;
    float4 v = *(const float4*)&ip[(size_t)(kt + r) * N + nt + cg * 4];
    tile[r][cg * 4 + 0] = v.x;
    tile[r][cg * 4 + 1] = v.y;
    tile[r][cg * 4 + 2] = v.z;
    tile[r][cg * 4 + 3] = v.w;
  }
  __syncthreads();
#pragma unroll
  for (int i = 0; i < 2; i++) {
    int rr = (tid >> 3) + i * 32;
    int kc = tid & 7;
    union { u16 u[8]; uint4 v; } r8;
#pragma unroll
    for (int j = 0; j < 8; j++) r8.u[j] = f2bf(tile[kc * 8 + j][rr]);
    *(uint4*)&op[(size_t)(nt + rr) * K + kt + kc * 8] = r8.v;
  }
}

// ---------------- gating (+ fused x fp32->bf16): one wave per token ----------------
__global__ void gate_kernel(const float* __restrict__ x, const float* __restrict__ Wg,
                            const float* __restrict__ bg, int* __restrict__ counts,
                            int* __restrict__ slot_tok, float* __restrict__ slot_w,
                            u16* __restrict__ xb) {
  const int t = blockIdx.x;
  const int lane = threadIdx.x;
  const float* xr = x + (size_t)t * DMODEL;
  float acc[NEXP];
#pragma unroll
  for (int e = 0; e < NEXP; e++) acc[e] = 0.f;
#pragma unroll
  for (int i = 0; i < 4; i++) {
    int k = (lane + i * 64) * 4;
    float4 xv = *(const float4*)&xr[k];
    union { u16 u[4]; uint2 v; } q;
    q.u[0] = f2bf(xv.x); q.u[1] = f2bf(xv.y); q.u[2] = f2bf(xv.z); q.u[3] = f2bf(xv.w);
    *(uint2*)&xb[(size_t)t * DMODEL + k] = q.v;
    const float* wr = &Wg[k * NEXP];
    float xa[4] = {xv.x, xv.y, xv.z, xv.w};
#pragma unroll
    for (int j = 0; j < 4; j++)
#pragma unroll
      for (int e = 0; e < NEXP; e++) acc[e] += xa[j] * wr[j * NEXP + e];
  }
#pragma unroll
  for (int off = 32; off >= 1; off >>= 1)
#pragma unroll
    for (int e = 0; e < NEXP; e++) acc[e] += __shfl_xor(acc[e], off);
  if (lane == 0) {
#pragma unroll
    for (int e = 0; e < NEXP; e++) acc[e] += bg[e];
    int i0 = 0; float v0 = acc[0];
#pragma unroll
    for (int e = 1; e < NEXP; e++) if (acc[e] > v0) { v0 = acc[e]; i0 = e; }
    int i1 = -1; float v1 = -3.0e38f;
#pragma unroll
    for (int e = 0; e < NEXP; e++) if (e != i0 && acc[e] > v1) { v1 = acc[e]; i1 = e; }
    float ex = __expf(v1 - v0);
    float inv = 1.0f / (1.0f + ex);
    int p0 = atomicAdd(&counts[i0], 1);
    slot_tok[i0 * TOKENS + p0] = t * 2;     slot_w[i0 * TOKENS + p0] = inv;
    int p1 = atomicAdd(&counts[i1], 1);
    slot_tok[i1 * TOKENS + p1] = t * 2 + 1; slot_w[i1 * TOKENS + p1] = ex * inv;
  }
}

// prefix over slots AND over 256-row m-tiles (compact GEMM work list)
__global__ void prefix_kernel(const int* __restrict__ counts, int* __restrict__ base,
                              int* __restrict__ t256) {
  if (threadIdx.x == 0) {
    int s = 0, ts = 0;
    for (int e = 0; e < NEXP; e++) {
      base[e] = s; t256[e] = ts;
      s += counts[e];
      ts += (counts[e] + 255) >> 8;
    }
    t256[NEXP] = ts;
  }
}

// ---------------- token -> (global slot, weight) inverse map ----------------
__global__ void build_map_kernel(const int* __restrict__ counts, const int* __restrict__ base,
                                 const int* __restrict__ slot_tok, const float* __restrict__ slot_w,
                                 int* __restrict__ tok_map, float* __restrict__ tok_w) {
  int e = blockIdx.y;
  int p = blockIdx.x * 256 + threadIdx.x;
  if (p < counts[e]) {
    int t2 = slot_tok[e * TOKENS + p];
    tok_map[t2] = base[e] + p;
    tok_w[t2] = slot_w[e * TOKENS + p];
  }
}

// ======================= 256x256 / BK=64 / 8-wave / 8-phase GEMMs =======================
// LDS tiles A,B: [256 rows][64 cols] bf16, double-buffered (128 KiB total).
// Swizzle: LDS(R, chunk c) holds global chunk c ^ (R&7)  (chunk = 16B unit, 8/row).
// Staging halves remapped to per-wave consumption:
//   A-sub h covers rows [0,64)+h*64 and [128,192)+h*64  (each wave-row-group's h-th 64 rows)
//   B-sub h covers rows [g*64, g*64+32)+h*32 for g=0..3
// Phase snake per K-tile: (A0,B0) (A0,B1) (A1,B1) (A1,B0); stage issue order A0,B0,B1,A1
// for the NEXT tile; uniform s_waitcnt vmcnt(4) before barrier#1 of every phase.
// Guard proof: phase p's ds_reads are covered by phase p-1's vmcnt(4)+barrier (collective).

// ---------------- GEMM1: H[slot, :] = relu(Xgather @ W1t^T + b1), bf16 out ----------------
__global__ __launch_bounds__(512, 2) void gemm1_kernel(
    const u16* __restrict__ xb, const u16* __restrict__ w1t, const float* __restrict__ b1,
    const int* __restrict__ slot_tok, const int* __restrict__ counts,
    const int* __restrict__ base, const int* __restrict__ t256, u16* __restrict__ H) {
  const int nwg = MAXT256 * 16;                 // 624, %8==0
  const int bid = (int)blockIdx.x;
  const int wg = (bid & 7) * (nwg >> 3) + (bid >> 3);   // XCD-chunked swizzle (T1)
  const int nt = wg & 15;
  const int trow = wg >> 4;
  if (trow >= t256[NEXP]) return;
  int e = 0;
#pragma unroll
  for (int i = 1; i < NEXP; i++) if (trow >= t256[i]) e = i;
  const int mt = trow - t256[e];
  const int cnt = counts[e];
  const int bse = base[e];
  const int tid = threadIdx.x;
  const int lane = tid & 63, wave = tid >> 6;
  const int wm = wave >> 2, wn = wave & 3;      // 2M x 4N waves; wave tile 128x64

  __shared__ __align__(16) u16 SM[65536];       // 128 KiB: A[2][16384] | B[2][16384]

  // ---- staging addresses ----
  const int l8 = lane >> 3, c8 = lane & 7;
  const int sc8 = (c8 ^ l8) * 8;                // swizzled source chunk offset (u16)
  const u16* agp[2][2]; int ldsA[2][2];
  const u16* bgp[2][2]; int ldsB[2][2];
  const u16* wbp = w1t + (size_t)e * DFF * DMODEL;
#pragma unroll
  for (int h = 0; h < 2; h++)
#pragma unroll
    for (int i = 0; i < 2; i++) {
      int rp = wave * 16 + i * 8 + l8;                       // [0,128)
      int Ra = (rp & 63) + ((rp >> 6) << 7) + h * 64;        // A-sub h actual row
      int ar = mt * 256 + Ra;
      int tok = (ar < cnt) ? (slot_tok[e * TOKENS + ar] >> 1) : 0;
      agp[h][i] = xb + (size_t)tok * DMODEL + sc8;
      ldsA[h][i] = Ra * 64 + c8 * 8;
      int Rb = (wave & 1) * 16 + i * 8 + l8 + ((wave >> 1) << 6) + h * 32;  // B-sub h
      bgp[h][i] = wbp + (size_t)(nt * 256 + Rb) * DMODEL + sc8;
      ldsB[h][i] = Rb * 64 + c8 * 8;
    }

#define G1_STAGE_A(h, nb, ko) do { \
    gl_lds16(agp[h][0] + (ko), &SM[(nb) * 16384 + ldsA[h][0]]); \
    gl_lds16(agp[h][1] + (ko), &SM[(nb) * 16384 + ldsA[h][1]]); } while (0)
#define G1_STAGE_B(h, nb, ko) do { \
    gl_lds16(bgp[h][0] + (ko), &SM[32768 + (nb) * 16384 + ldsB[h][0]]); \
    gl_lds16(bgp[h][1] + (ko), &SM[32768 + (nb) * 16384 + ldsB[h][1]]); } while (0)

  // ---- fragment lane offsets ----
  const int l15 = lane & 15;
  int laneK[2];
#pragma unroll
  for (int kk = 0; kk < 2; kk++)
    laneK[kk] = l15 * 64 + (((kk * 4 + (lane >> 4)) ^ (lane & 7)) * 8);

  f32x4 acc[8][4] = {};
  short8 af[4][2], bf[2][2];
  const int NT = DMODEL / 64;   // 16

  // ---- prologue: stage tile 0 (order A0,B0,B1,A1), retire A0,B0 ----
  G1_STAGE_A(0, 0, 0); CFENCE();
  G1_STAGE_B(0, 0, 0); CFENCE();
  G1_STAGE_B(1, 0, 0); CFENCE();
  G1_STAGE_A(1, 0, 0); CFENCE();
  VMCNT4();
  __builtin_amdgcn_s_barrier();
  CFENCE();

  for (int t = 0; t < NT; ++t) {
    const int cb = (t & 1) * 16384, nb = (t & 1) ^ 1;
    const int ko = (t + 1 < NT) ? (t + 1) * 64 : 0;   // last tile: harmless dummy stages

    // ---- phase 1: (A0 x B0) ----
#pragma unroll
    for (int i = 0; i < 4; i++)
#pragma unroll
      for (int kk = 0; kk < 2; kk++)
        af[i][kk] = *(const short8*)&SM[cb + (wm * 128 + i * 16) * 64 + laneK[kk]];
#pragma unroll
    for (int j = 0; j < 2; j++)
#pragma unroll
      for (int kk = 0; kk < 2; kk++)
        bf[j][kk] = *(const short8*)&SM[32768 + cb + (wn * 64 + j * 16) * 64 + laneK[kk]];
    G1_STAGE_A(0, nb, ko);
    VMCNT4();
    __builtin_amdgcn_s_barrier(); CFENCE();
    __builtin_amdgcn_s_setprio(1);
#pragma unroll
    for (int kk = 0; kk < 2; kk++)
#pragma unroll
      for (int i = 0; i < 4; i++)
#pragma unroll
        for (int j = 0; j < 2; j++)
          acc[i][j] = __builtin_amdgcn_mfma_f32_16x16x32_bf16(af[i][kk], bf[j][kk], acc[i][j], 0, 0, 0);
    __builtin_amdgcn_s_setprio(0);
    __builtin_amdgcn_s_barrier(); CFENCE();

    // ---- phase 2: (A0 x B1) ----
#pragma unroll
    for (int j = 0; j < 2; j++)
#pragma unroll
      for (int kk = 0; kk < 2; kk++)
        bf[j][kk] = *(const short8*)&SM[32768 + cb + (wn * 64 + 32 + j * 16) * 64 + laneK[kk]];
    G1_STAGE_B(0, nb, ko);
    VMCNT4();
    __builtin_amdgcn_s_barrier(); CFENCE();
    __builtin_amdgcn_s_setprio(1);
#pragma unroll
    for (int kk = 0; kk < 2; kk++)
#pragma unroll
      for (int i = 0; i < 4; i++)
#pragma unroll
        for (int j = 0; j < 2; j++)
          acc[i][2 + j] = __builtin_amdgcn_mfma_f32_16x16x32_bf16(af[i][kk], bf[j][kk], acc[i][2 + j], 0, 0, 0);
    __builtin_amdgcn_s_setprio(0);
    __builtin_amdgcn_s_barrier(); CFENCE();

    // ---- phase 3: (A1 x B1) ----
#pragma unroll
    for (int i = 0; i < 4; i++)
#pragma unroll
      for (int kk = 0; kk < 2; kk++)
        af[i][kk] = *(const short8*)&SM[cb + (wm * 128 + 64 + i * 16) * 64 + laneK[kk]];
    G1_STAGE_B(1, nb, ko);
    VMCNT4();
    __builtin_amdgcn_s_barrier(); CFENCE();
    __builtin_amdgcn_s_setprio(1);
#pragma unroll
    for (int kk = 0; kk < 2; kk++)
#pragma unroll
      for (int i = 0; i < 4; i++)
#pragma unroll
        for (int j = 0; j < 2; j++)
          acc[4 + i][2 + j] = __builtin_amdgcn_mfma_f32_16x16x32_bf16(af[i][kk], bf[j][kk], acc[4 + i][2 + j], 0, 0, 0);
    __builtin_amdgcn_s_setprio(0);
    __builtin_amdgcn_s_barrier(); CFENCE();

    // ---- phase 4: (A1 x B0) ----
#pragma unroll
    for (int j = 0; j < 2; j++)
#pragma unroll
      for (int kk = 0; kk < 2; kk++)
        bf[j][kk] = *(const short8*)&SM[32768 + cb + (wn * 64 + j * 16) * 64 + laneK[kk]];
    G1_STAGE_A(1, nb, ko);
    VMCNT4();
    __builtin_amdgcn_s_barrier(); CFENCE();
    __builtin_amdgcn_s_setprio(1);
#pragma unroll
    for (int kk = 0; kk < 2; kk++)
#pragma unroll
      for (int i = 0; i < 4; i++)
#pragma unroll
        for (int j = 0; j < 2; j++)
          acc[4 + i][j] = __builtin_amdgcn_mfma_f32_16x16x32_bf16(af[i][kk], bf[j][kk], acc[4 + i][j], 0, 0, 0);
    __builtin_amdgcn_s_setprio(0);
    __builtin_amdgcn_s_barrier(); CFENCE();
  }

  // ---- epilogue: bias+relu+cvt into LDS 256x256 bf16 tile, coalesced b128 stores ----
  __syncthreads();   // full drain (vmcnt0 + lgkm0) before SM reuse
  const int rq = (lane >> 4) * 4;
#pragma unroll
  for (int ni = 0; ni < 4; ni++) {
    const int col = wn * 64 + ni * 16 + l15;
    const float bv = b1[e * DFF + nt * 256 + col];
#pragma unroll
    for (int mi = 0; mi < 8; mi++)
#pragma unroll
      for (int r = 0; r < 4; r++) {
        int row = wm * 128 + mi * 16 + rq + r;
        float v = acc[mi][ni][r] + bv;
        SM[row * 256 + col] = f2bf(v > 0.f ? v : 0.f);
      }
  }
  __syncthreads();
#pragma unroll
  for (int rep = 0; rep < 16; rep++) {
    int idx = rep * 512 + tid;          // 8192 = 256 rows x 32 chunks
    int r = idx >> 5, ch = idx & 31;
    int grow = mt * 256 + r;
    if (grow < cnt)
      *(uint4*)&H[(size_t)(bse + grow) * DFF + nt * 256 + ch * 8] =
          *(const uint4*)&SM[r * 256 + ch * 8];
  }
#undef G1_STAGE_A
#undef G1_STAGE_B
}

// ------- GEMM2 (K-split x2): Yp[ks][slot, :] = H @ W2t^T (+ b2 on ks=0) -------
__global__ __launch_bounds__(512, 2) void gemm2_kernel(
    const u16* __restrict__ H, const u16* __restrict__ w2t, const float* __restrict__ b2,
    const int* __restrict__ counts, const int* __restrict__ base,
    const int* __restrict__ t256, float* __restrict__ Yp) {
  const int nwg = MAXT256 * 8;                  // 312, %8==0
  const int bid = (int)blockIdx.x;
  const int wg = (bid & 7) * (nwg >> 3) + (bid >> 3);
  const int nks = wg & 7;
  const int nt = nks & 3, ks = nks >> 2;
  const int trow = wg >> 3;
  if (trow >= t256[NEXP]) return;
  int e = 0;
#pragma unroll
  for (int i = 1; i < NEXP; i++) if (trow >= t256[i]) e = i;
  const int mt = trow - t256[e];
  const int cnt = counts[e];
  const int bse = base[e];
  const int kbeg = ks * (DFF / KS2);
  const int tid = threadIdx.x;
  const int lane = tid & 63, wave = tid >> 6;
  const int wm = wave >> 2, wn = wave & 3;

  __shared__ __align__(16) u16 SM[65536];

  const int l8 = lane >> 3, c8 = lane & 7;
  const int sc8 = (c8 ^ l8) * 8;
  const u16* agp[2][2]; int ldsA[2][2];
  const u16* bgp[2][2]; int ldsB[2][2];
  const u16* wbp = w2t + (size_t)e * DMODEL * DFF;
#pragma unroll
  for (int h = 0; h < 2; h++)
#pragma unroll
    for (int i = 0; i < 2; i++) {
      int rp = wave * 16 + i * 8 + l8;
      int Ra = (rp & 63) + ((rp >> 6) << 7) + h * 64;
      int ar = mt * 256 + Ra;
      int hr = bse + ((ar < cnt) ? ar : 0);
      agp[h][i] = H + (size_t)hr * DFF + kbeg + sc8;
      ldsA[h][i] = Ra * 64 + c8 * 8;
      int Rb = (wave & 1) * 16 + i * 8 + l8 + ((wave >> 1) << 6) + h * 32;
      bgp[h][i] = wbp + (size_t)(nt * 256 + Rb) * DFF + kbeg + sc8;
      ldsB[h][i] = Rb * 64 + c8 * 8;
    }

#define G2_STAGE_A(h, nb, ko) do { \
    gl_lds16(agp[h][0] + (ko), &SM[(nb) * 16384 + ldsA[h][0]]); \
    gl_lds16(agp[h][1] + (ko), &SM[(nb) * 16384 + ldsA[h][1]]); } while (0)
#define G2_STAGE_B(h, nb, ko) do { \
    gl_lds16(bgp[h][0] + (ko), &SM[32768 + (nb) * 16384 + ldsB[h][0]]); \
    gl_lds16(bgp[h][1] + (ko), &SM[32768 + (nb) * 16384 + ldsB[h][1]]); } while (0)

  const int l15 = lane & 15;
  int laneK[2];
#pragma unroll
  for (int kk = 0; kk < 2; kk++)
    laneK[kk] = l15 * 64 + (((kk * 4 + (lane >> 4)) ^ (lane & 7)) * 8);

  f32x4 acc[8][4] = {};
  short8 af[4][2], bf[2][2];
  const int NT = (DFF / KS2) / 64;   // 32

  G2_STAGE_A(0, 0, 0); CFENCE();
  G2_STAGE_B(0, 0, 0); CFENCE();
  G2_STAGE_B(1, 0, 0); CFENCE();
  G2_STAGE_A(1, 0, 0); CFENCE();
  VMCNT4();
  __builtin_amdgcn_s_barrier();
  CFENCE();

  for (int t = 0; t < NT; ++t) {
    const int cb = (t & 1) * 16384, nb = (t & 1) ^ 1;
    const int ko = (t + 1 < NT) ? (t + 1) * 64 : 0;

    // phase 1
#pragma unroll
    for (int i = 0; i < 4; i++)
#pragma unroll
      for (int kk = 0; kk < 2; kk++)
        af[i][kk] = *(const short8*)&SM[cb + (wm * 128 + i * 16) * 64 + laneK[kk]];
#pragma unroll
    for (int j = 0; j < 2; j++)
#pragma unroll
      for (int kk = 0; kk < 2; kk++)
        bf[j][kk] = *(const short8*)&SM[32768 + cb + (wn * 64 + j * 16) * 64 + laneK[kk]];
    G2_STAGE_A(0, nb, ko);
    VMCNT4();
    __builtin_amdgcn_s_barrier(); CFENCE();
    __builtin_amdgcn_s_setprio(1);
#pragma unroll
    for (int kk = 0; kk < 2; kk++)
#pragma unroll
      for (int i = 0; i < 4; i++)
#pragma unroll
        for (int j = 0; j < 2; j++)
          acc[i][j] = __builtin_amdgcn_mfma_f32_16x16x32_bf16(af[i][kk], bf[j][kk], acc[i][j], 0, 0, 0);
    __builtin_amdgcn_s_setprio(0);
    __builtin_amdgcn_s_barrier(); CFENCE();

    // phase 2
#pragma unroll
    for (int j = 0; j < 2; j++)
#pragma unroll
      for (int kk = 0; kk < 2; kk++)
        bf[j][kk] = *(const short8*)&SM[32768 + cb + (wn * 64 + 32 + j * 16) * 64 + laneK[kk]];
    G2_STAGE_B(0, nb, ko);
    VMCNT4();
    __builtin_amdgcn_s_barrier(); CFENCE();
    __builtin_amdgcn_s_setprio(1);
#pragma unroll
    for (int kk = 0; kk < 2; kk++)
#pragma unroll
      for (int i = 0; i < 4; i++)
#pragma unroll
        for (int j = 0; j < 2; j++)
          acc[i][2 + j] = __builtin_amdgcn_mfma_f32_16x16x32_bf16(af[i][kk], bf[j][kk], acc[i][2 + j], 0, 0, 0);
    __builtin_amdgcn_s_setprio(0);
    __builtin_amdgcn_s_barrier(); CFENCE();

    // phase 3
#pragma unroll
    for (int i = 0; i < 4; i++)
#pragma unroll
      for (int kk = 0; kk < 2; kk++)
        af[i][kk] = *(const short8*)&SM[cb + (wm * 128 + 64 + i * 16) * 64 + laneK[kk]];
    G2_STAGE_B(1, nb, ko);
    VMCNT4();
    __builtin_amdgcn_s_barrier(); CFENCE();
    __builtin_amdgcn_s_setprio(1);
#pragma unroll
    for (int kk = 0; kk < 2; kk++)
#pragma unroll
      for (int i = 0; i < 4; i++)
#pragma unroll
        for (int j = 0; j < 2; j++)
          acc[4 + i][2 + j] = __builtin_amdgcn_mfma_f32_16x16x32_bf16(af[i][kk], bf[j][kk], acc[4 + i][2 + j], 0, 0, 0);
    __builtin_amdgcn_s_setprio(0);
    __builtin_amdgcn_s_barrier(); CFENCE();

    // phase 4
#pragma unroll
    for (int j = 0; j < 2; j++)
#pragma unroll
      for (int kk = 0; kk < 2; kk++)
        bf[j][kk] = *(const short8*)&SM[32768 + cb + (wn * 64 + j * 16) * 64 + laneK[kk]];
    G2_STAGE_A(1, nb, ko);
    VMCNT4();
    __builtin_amdgcn_s_barrier(); CFENCE();
    __builtin_amdgcn_s_setprio(1);
#pragma unroll
    for (int kk = 0; kk < 2; kk++)
#pragma unroll
      for (int i = 0; i < 4; i++)
#pragma unroll
        for (int j = 0; j < 2; j++)
          acc[4 + i][j] = __builtin_amdgcn_mfma_f32_16x16x32_bf16(af[i][kk], bf[j][kk], acc[4 + i][j], 0, 0, 0);
    __builtin_amdgcn_s_setprio(0);
    __builtin_amdgcn_s_barrier(); CFENCE();
  }

  // ---- epilogue: fp32 repack through LDS in two 128-row passes, float4 stores ----
  __syncthreads();
  float* FB = (float*)SM;              // 128 x 256 f32 = 128 KiB
  float* yb = Yp + (size_t)ks * SLOTS * DMODEL;
  float bv[4];
#pragma unroll
  for (int ni = 0; ni < 4; ni++)
    bv[ni] = (ks == 0) ? b2[e * DMODEL + nt * 256 + wn * 64 + ni * 16 + l15] : 0.f;
  const int rq = (lane >> 4) * 4;
#pragma unroll
  for (int h = 0; h < 2; h++) {
    if (wm == h) {
#pragma unroll
      for (int mi = 0; mi < 8; mi++)
#pragma unroll
        for (int ni = 0; ni < 4; ni++)
#pragma unroll
          for (int r = 0; r < 4; r++)
            FB[(mi * 16 + rq + r) * 256 + wn * 64 + ni * 16 + l15] = acc[mi][ni][r] + bv[ni];
    }
    __syncthreads();
#pragma unroll
    for (int rep = 0; rep < 16; rep++) {
      int idx = rep * 512 + tid;       // 8192 = 128 rows x 64 float4
      int lr = idx >> 6, c4 = idx & 63;
      int grow = mt * 256 + h * 128 + lr;
      if (grow < cnt)
        *(float4*)&yb[(size_t)(bse + grow) * DMODEL + nt * 256 + c4 * 4] =
            *(const float4*)&FB[lr * 256 + c4 * 4];
    }
    __syncthreads();
  }
#undef G2_STAGE_A
#undef G2_STAGE_B
}

// ---------------- combine: out[t] = w0*(Yp0[s0]+Yp1[s0]) + w1*(Yp0[s1]+Yp1[s1]) ----------------
__global__ void combine_kernel(const float* __restrict__ Yp, const int* __restrict__ tok_map,
                               const float* __restrict__ tok_w, float* __restrict__ out) {
  const int t = blockIdx.x;
  const int s0 = tok_map[2 * t], s1 = tok_map[2 * t + 1];
  const float w0 = tok_w[2 * t], w1 = tok_w[2 * t + 1];
  const int i = threadIdx.x * 4;
  const float* y0a = Yp + (size_t)s0 * DMODEL;
  const float* y0b = y0a + (size_t)SLOTS * DMODEL;
  const float* y1a = Yp + (size_t)s1 * DMODEL;
  const float* y1b = y1a + (size_t)SLOTS * DMODEL;
  float4 a = *(const float4*)&y0a[i];
  float4 b = *(const float4*)&y0b[i];
  float4 c = *(const float4*)&y1a[i];
  float4 d = *(const float4*)&y1b[i];
  float4 r;
  r.x = w0 * (a.x + b.x) + w1 * (c.x + d.x);
  r.y = w0 * (a.y + b.y) + w1 * (c.y + d.y);
  r.z = w0 * (a.z + b.z) + w1 * (c.z + d.z);
  r.w = w0 * (a.w + b.w) + w1 * (c.w + d.w);
  *(float4*)&out[(size_t)t * DMODEL + i] = r;
}

extern "C" void kernel_launch(void* const* d_in, const int* in_sizes, int n_in,
                              void* d_out, int out_size, void* d_ws, size_t ws_size,
                              hipStream_t stream) {
  const float* x  = (const float*)d_in[0];
  const float* Wg = (const float*)d_in[1];
  const float* bg = (const float*)d_in[2];
  const float* W1 = (const float*)d_in[3];
  const float* b1 = (const float*)d_in[4];
  const float* W2 = (const float*)d_in[5];
  const float* b2 = (const float*)d_in[6];
  float* out = (float*)d_out;

  char* p = (char*)d_ws;
  int*   counts   = (int*)p;   p += 256;
  int*   base     = (int*)p;   p += 256;
  int*   t256     = (int*)p;   p += 256;
  int*   slot_tok = (int*)p;   p += (size_t)NEXP * TOKENS * 4;
  float* slot_w   = (float*)p; p += (size_t)NEXP * TOKENS * 4;
  int*   tok_map  = (int*)p;   p += (size_t)SLOTS * 4;
  float* tok_w    = (float*)p; p += (size_t)SLOTS * 4;
  u16*   xb       = (u16*)p;   p += (size_t)TOKENS * DMODEL * 2;
  u16*   w1t      = (u16*)p;   p += (size_t)NEXP * DMODEL * DFF * 2;   // 64 MB
  u16*   w2t      = (u16*)p;   p += (size_t)NEXP * DMODEL * DFF * 2;   // 64 MB
  u16*   H        = (u16*)p;   p += (size_t)SLOTS * DFF * 2;           // 64 MB
  // Yp (2 x 32 MB fp32 partials) ALIASES w1t: dead after gemm1; gemm2 ordered after.
  float* Yp = (float*)w1t;

  (void)hipMemsetAsync(counts, 0, 256, stream);

  transpose_cvt_kernel<<<dim3(1024, 1, 16), 256, 0, stream>>>(W1, w1t, W2, w2t);
  gate_kernel<<<TOKENS, 64, 0, stream>>>(x, Wg, bg, counts, slot_tok, slot_w, xb);
  prefix_kernel<<<1, 64, 0, stream>>>(counts, base, t256);
  build_map_kernel<<<dim3(TOKENS / 256, NEXP), 256, 0, stream>>>(
      counts, base, slot_tok, slot_w, tok_map, tok_w);
  gemm1_kernel<<<MAXT256 * 16, 512, 0, stream>>>(
      xb, w1t, b1, slot_tok, counts, base, t256, H);
  gemm2_kernel<<<MAXT256 * 8, 512, 0, stream>>>(
      H, w2t, b2, counts, base, t256, Yp);
  combine_kernel<<<TOKENS, 256, 0, stream>>>(Yp, tok_map, tok_w, out);
}

// Round 3
// 641.703 us; speedup vs baseline: 1.0384x; 1.0125x over previous
//
#include <hip/hip_runtime.h>
#include <cstdint>

#define TOKENS 4096
#define DMODEL 1024
#define DFF    4096
#define NEXP   8
#define SLOTS  (2 * TOKENS)   // 8192 (token,expert) pairs
#define KS2    2              // K-split for gemm2 (4096 -> 2 x 2048), partial Y buffers
#define MAXT   71             // max total m-tiles: floor(8192/128) + 7

typedef unsigned short u16;
typedef __attribute__((ext_vector_type(8))) short short8;   // 8 bf16 (4 VGPRs)
typedef __attribute__((ext_vector_type(4))) float f32x4;

__device__ __forceinline__ u16 f2bf(float f) {
  union { float f; uint32_t u; } c; c.f = f;
  uint32_t u = c.u;
  u += 0x7fffu + ((u >> 16) & 1u);   // round-to-nearest-even
  return (u16)(u >> 16);
}

__device__ __forceinline__ void gl_lds16(const void* g, void* l) {
  __builtin_amdgcn_global_load_lds((__attribute__((address_space(1))) void*)(g),
                                   (__attribute__((address_space(3))) void*)(l),
                                   16, 0, 0);
}

#define CFENCE() asm volatile("" ::: "memory")

// ------- W [E][K][N] fp32 -> [E][N][K] bf16 (K-major for MFMA operands) -------
__global__ void transpose_cvt_kernel(const float* __restrict__ W1, u16* __restrict__ w1t,
                                     const float* __restrict__ W2, u16* __restrict__ w2t) {
  const int z = blockIdx.z;
  int K, N; const float* ip; u16* op;
  if (z < 8) { K = DMODEL; N = DFF;    ip = W1 + (size_t)z * K * N;       op = w1t + (size_t)z * K * N; }
  else       { K = DFF;    N = DMODEL; ip = W2 + (size_t)(z - 8) * K * N; op = w2t + (size_t)(z - 8) * K * N; }
  const int ntn = N >> 6;
  const int nt = (blockIdx.x & (ntn - 1)) << 6;
  const int kt = (blockIdx.x / ntn) << 6;

  __shared__ float tile[64][65];
  const int tid = threadIdx.x;
#pragma unroll
  for (int i = 0; i < 4; i++) {
    int idx = tid + i * 256;
    int r = idx >> 4, cg = idx & 15;
    float4 v = *(const float4*)&ip[(size_t)(kt + r) * N + nt + cg * 4];
    tile[r][cg * 4 + 0] = v.x;
    tile[r][cg * 4 + 1] = v.y;
    tile[r][cg * 4 + 2] = v.z;
    tile[r][cg * 4 + 3] = v.w;
  }
  __syncthreads();
#pragma unroll
  for (int i = 0; i < 2; i++) {
    int rr = (tid >> 3) + i * 32;
    int kc = tid & 7;
    union { u16 u[8]; uint4 v; } r8;
#pragma unroll
    for (int j = 0; j < 8; j++) r8.u[j] = f2bf(tile[kc * 8 + j][rr]);
    *(uint4*)&op[(size_t)(nt + rr) * K + kt + kc * 8] = r8.v;
  }
}

// ---------------- gating (+ fused x fp32->bf16): one wave per token ----------------
__global__ void gate_kernel(const float* __restrict__ x, const float* __restrict__ Wg,
                            const float* __restrict__ bg, int* __restrict__ counts,
                            int* __restrict__ slot_tok, float* __restrict__ slot_w,
                            u16* __restrict__ xb) {
  const int t = blockIdx.x;
  const int lane = threadIdx.x;
  const float* xr = x + (size_t)t * DMODEL;
  float acc[NEXP];
#pragma unroll
  for (int e = 0; e < NEXP; e++) acc[e] = 0.f;
#pragma unroll
  for (int i = 0; i < 4; i++) {
    int k = (lane + i * 64) * 4;
    float4 xv = *(const float4*)&xr[k];
    union { u16 u[4]; uint2 v; } q;
    q.u[0] = f2bf(xv.x); q.u[1] = f2bf(xv.y); q.u[2] = f2bf(xv.z); q.u[3] = f2bf(xv.w);
    *(uint2*)&xb[(size_t)t * DMODEL + k] = q.v;
    const float* wr = &Wg[k * NEXP];
    float xa[4] = {xv.x, xv.y, xv.z, xv.w};
#pragma unroll
    for (int j = 0; j < 4; j++)
#pragma unroll
      for (int e = 0; e < NEXP; e++) acc[e] += xa[j] * wr[j * NEXP + e];
  }
#pragma unroll
  for (int off = 32; off >= 1; off >>= 1)
#pragma unroll
    for (int e = 0; e < NEXP; e++) acc[e] += __shfl_xor(acc[e], off);
  if (lane == 0) {
#pragma unroll
    for (int e = 0; e < NEXP; e++) acc[e] += bg[e];
    int i0 = 0; float v0 = acc[0];
#pragma unroll
    for (int e = 1; e < NEXP; e++) if (acc[e] > v0) { v0 = acc[e]; i0 = e; }
    int i1 = -1; float v1 = -3.0e38f;
#pragma unroll
    for (int e = 0; e < NEXP; e++) if (e != i0 && acc[e] > v1) { v1 = acc[e]; i1 = e; }
    float ex = __expf(v1 - v0);
    float inv = 1.0f / (1.0f + ex);
    int p0 = atomicAdd(&counts[i0], 1);
    slot_tok[i0 * TOKENS + p0] = t * 2;     slot_w[i0 * TOKENS + p0] = inv;
    int p1 = atomicAdd(&counts[i1], 1);
    slot_tok[i1 * TOKENS + p1] = t * 2 + 1; slot_w[i1 * TOKENS + p1] = ex * inv;
  }
}

// prefix over slots AND over m-tiles (compact GEMM work list)
__global__ void prefix_kernel(const int* __restrict__ counts, int* __restrict__ base,
                              int* __restrict__ tstart) {
  if (threadIdx.x == 0) {
    int s = 0, ts = 0;
    for (int e = 0; e < NEXP; e++) {
      base[e] = s; tstart[e] = ts;
      s += counts[e];
      ts += (counts[e] + 127) >> 7;
    }
    tstart[NEXP] = ts;
  }
}

// ---------------- token -> (global slot, weight) inverse map ----------------
__global__ void build_map_kernel(const int* __restrict__ counts, const int* __restrict__ base,
                                 const int* __restrict__ slot_tok, const float* __restrict__ slot_w,
                                 int* __restrict__ tok_map, float* __restrict__ tok_w) {
  int e = blockIdx.y;
  int p = blockIdx.x * 256 + threadIdx.x;
  if (p < counts[e]) {
    int t2 = slot_tok[e * TOKENS + p];
    tok_map[t2] = base[e] + p;
    tok_w[t2] = slot_w[e * TOKENS + p];
  }
}

// LDS bank-conflict swizzle for the 128x32-u16 staging tiles (64 B rows):
// LDS 16B-chunk (row r, chunk c) holds global chunk (r, c ^ ((r>>1)&3)).
__device__ __forceinline__ int swz_koff(int c) {           // staging thread c -> u16 offset
  return (((c & 3) ^ ((c >> 3) & 3)) * 8);
}
__device__ __forceinline__ int swz_read(int R, int chunk) { // row R, wanted chunk -> u16 offset
  return R * 32 + ((chunk ^ ((R >> 1) & 3)) * 8);
}

// =================== 128x128 / BK=32 / 4-wave GEMMs, counted-vmcnt schedule ===================
// Per K-step: [stage(t+1) -> s_waitcnt vmcnt(4) -> s_barrier -> ds_read+MFMA -> s_barrier].
// vmcnt(4) retires exactly stage(t) (oldest 4 of 8 outstanding); following barrier makes the
// guarantee collective. Next-tile loads (4) stay in flight across the compute phase — the
// per-step vmcnt(0)+lgkmcnt(0) drain of __syncthreads (the m97-structure stall) is gone.
// bar2 orders buf-s reads (completed before their MFMA consumers via compiler lgkmcnt)
// against stage(t+2)'s overwrite of buf s.

// ---------------- GEMM1: H[slot, :] = relu(Xgather @ W1t^T + b1), bf16 out ----------------
__global__ __launch_bounds__(256, 4) void gemm1_kernel(
    const u16* __restrict__ xb, const u16* __restrict__ w1t, const float* __restrict__ b1,
    const int* __restrict__ slot_tok, const int* __restrict__ counts,
    const int* __restrict__ base, const int* __restrict__ tstart, u16* __restrict__ H) {
  const int nwg = MAXT * 32;                    // 2272, %8==0
  const int bid = (int)blockIdx.x;
  const int wg = (bid & 7) * (nwg >> 3) + (bid >> 3);   // bijective XCD-chunk swizzle (T1)
  const int nt = wg & 31;
  const int trow = wg >> 5;
  if (trow >= tstart[NEXP]) return;
  int e = 0;
#pragma unroll
  for (int i = 1; i < NEXP; i++) if (trow >= tstart[i]) e = i;
  const int mt = trow - tstart[e];
  const int cnt = counts[e];
  const int bse = base[e];
  const int tid = threadIdx.x;
  const int lane = tid & 63, wave = tid >> 6;
  const int wm = wave & 1, wn = wave >> 1;

  // 32 KB flat LDS: [As0 | As1 | Bs0 | Bs1], each 128x32 u16 (8 KB).
  // Epilogue reuses the whole 16384-u16 region as a 128x128 bf16 tile.
  __shared__ __align__(16) u16 SM[16384];

  const int c0 = tid, c1 = tid + 256;           // each: row=c>>2, kchunk=c&3
  const int ar0 = mt * 128 + (c0 >> 2), ar1 = mt * 128 + (c1 >> 2);
  const int t0 = (ar0 < cnt) ? (slot_tok[e * TOKENS + ar0] >> 1) : 0;
  const int t1 = (ar1 < cnt) ? (slot_tok[e * TOKENS + ar1] >> 1) : 0;
  const u16* ag0 = xb + (size_t)t0 * DMODEL + swz_koff(c0);
  const u16* ag1 = xb + (size_t)t1 * DMODEL + swz_koff(c1);
  const u16* wb  = w1t + (size_t)e * DFF * DMODEL;
  const u16* bg0 = wb + (size_t)(nt * 128 + (c0 >> 2)) * DMODEL + swz_koff(c0);
  const u16* bg1 = wb + (size_t)(nt * 128 + (c1 >> 2)) * DMODEL + swz_koff(c1);

  f32x4 acc[4][4] = {};
  const int mr = wm * 64 + (lane & 15);
  const int nr = wn * 64 + (lane & 15);
  const int ch = lane >> 4;                     // wanted 16B k-chunk
  const int NIT = DMODEL / 32;

  // per-lane swizzled read offsets (loop-invariant; only s*4096 varies)
  int offA[4], offB[4];
#pragma unroll
  for (int i = 0; i < 4; i++) {
    offA[i] = swz_read(mr + i * 16, ch);
    offB[i] = 8192 + swz_read(nr + i * 16, ch);
  }

  // prologue: stage iter 0 into buffer 0 (4 outstanding)
  gl_lds16(ag0, &SM[c0 * 8]);
  gl_lds16(ag1, &SM[c1 * 8]);
  gl_lds16(bg0, &SM[8192 + c0 * 8]);
  gl_lds16(bg1, &SM[8192 + c1 * 8]);
  CFENCE();

  int s = 0;
  for (int it = 0; it < NIT; ++it, s ^= 1) {
    if (it + 1 < NIT) {
      int k1 = (it + 1) * 32;
      gl_lds16(ag0 + k1, &SM[(s ^ 1) * 4096 + c0 * 8]);
      gl_lds16(ag1 + k1, &SM[(s ^ 1) * 4096 + c1 * 8]);
      gl_lds16(bg0 + k1, &SM[8192 + (s ^ 1) * 4096 + c0 * 8]);
      gl_lds16(bg1 + k1, &SM[8192 + (s ^ 1) * 4096 + c1 * 8]);
      CFENCE();
      asm volatile("s_waitcnt vmcnt(4)" ::: "memory");   // stage(it) done; stage(it+1) in flight
    } else {
      asm volatile("s_waitcnt vmcnt(0)" ::: "memory");   // final tile: full drain
    }
    __builtin_amdgcn_s_barrier();
    CFENCE();
    short8 af[4], bf[4];
#pragma unroll
    for (int i = 0; i < 4; i++) af[i] = *(const short8*)&SM[s * 4096 + offA[i]];
#pragma unroll
    for (int i = 0; i < 4; i++) bf[i] = *(const short8*)&SM[s * 4096 + offB[i]];
    __builtin_amdgcn_s_setprio(1);
#pragma unroll
    for (int mi = 0; mi < 4; mi++)
#pragma unroll
      for (int ni = 0; ni < 4; ni++)
        acc[mi][ni] = __builtin_amdgcn_mfma_f32_16x16x32_bf16(af[mi], bf[ni], acc[mi][ni], 0, 0, 0);
    __builtin_amdgcn_s_setprio(0);
    __builtin_amdgcn_s_barrier();    // buf-s reads done (lgkm-guarded) before next overwrite
    CFENCE();
  }

  // ---- epilogue: bias+relu+cvt into LDS tile, then coalesced b128 stores ----
  __syncthreads();   // full drain before SM reuse
  const int rq = (lane >> 4) * 4;
#pragma unroll
  for (int ni = 0; ni < 4; ni++) {
    const int col = wn * 64 + ni * 16 + (lane & 15);
    const float bv = b1[e * DFF + nt * 128 + col];
#pragma unroll
    for (int mi = 0; mi < 4; mi++)
#pragma unroll
      for (int r = 0; r < 4; r++) {
        int row = wm * 64 + mi * 16 + rq + r;
        float v = acc[mi][ni][r] + bv;
        SM[row * 128 + col] = f2bf(v > 0.f ? v : 0.f);
      }
  }
  __syncthreads();
#pragma unroll
  for (int rep = 0; rep < 8; rep++) {
    int idx = rep * 256 + tid;          // 2048 = 128 rows x 16 chunks
    int r = idx >> 4, chk = idx & 15;
    int grow = mt * 128 + r;
    if (grow < cnt)
      *(uint4*)&H[(size_t)(bse + grow) * DFF + nt * 128 + chk * 8] =
          *(const uint4*)&SM[r * 128 + chk * 8];
  }
}

// ------- GEMM2 (K-split x2, no atomics): Yp[ks][slot, :] = H @ W2t^T (+ b2 on ks=0) -------
__global__ __launch_bounds__(256, 4) void gemm2_kernel(
    const u16* __restrict__ H, const u16* __restrict__ w2t, const float* __restrict__ b2,
    const int* __restrict__ counts, const int* __restrict__ base,
    const int* __restrict__ tstart, float* __restrict__ Yp) {
  const int nwg = MAXT * 16;                    // 1136, %8==0
  const int bid = (int)blockIdx.x;
  const int wg = (bid & 7) * (nwg >> 3) + (bid >> 3);
  const int nks = wg & 15;
  const int nt = nks & 7, ks = nks >> 3;
  const int trow = wg >> 4;
  if (trow >= tstart[NEXP]) return;
  int e = 0;
#pragma unroll
  for (int i = 1; i < NEXP; i++) if (trow >= tstart[i]) e = i;
  const int mt = trow - tstart[e];
  const int cnt = counts[e];
  const int bse = base[e];
  const int kbeg = ks * (DFF / KS2);
  const int tid = threadIdx.x;
  const int lane = tid & 63, wave = tid >> 6;
  const int wm = wave & 1, wn = wave >> 1;

  __shared__ __align__(16) u16 As[2][128 * 32];
  __shared__ __align__(16) u16 Bs[2][128 * 32];

  const int c0 = tid, c1 = tid + 256;
  const int ar0 = mt * 128 + (c0 >> 2), ar1 = mt * 128 + (c1 >> 2);
  const int hr0 = bse + ((ar0 < cnt) ? ar0 : 0);
  const int hr1 = bse + ((ar1 < cnt) ? ar1 : 0);
  const u16* ag0 = H + (size_t)hr0 * DFF + kbeg + swz_koff(c0);
  const u16* ag1 = H + (size_t)hr1 * DFF + kbeg + swz_koff(c1);
  const u16* wb  = w2t + (size_t)e * DMODEL * DFF;
  const u16* bg0 = wb + (size_t)(nt * 128 + (c0 >> 2)) * DFF + kbeg + swz_koff(c0);
  const u16* bg1 = wb + (size_t)(nt * 128 + (c1 >> 2)) * DFF + kbeg + swz_koff(c1);

  f32x4 acc[4][4] = {};
  const int mr = wm * 64 + (lane & 15);
  const int nr = wn * 64 + (lane & 15);
  const int ch = lane >> 4;
  const int NIT = (DFF / KS2) / 32;

  int offA[4], offB[4];
#pragma unroll
  for (int i = 0; i < 4; i++) {
    offA[i] = swz_read(mr + i * 16, ch);
    offB[i] = swz_read(nr + i * 16, ch);
  }

  gl_lds16(ag0, &As[0][c0 * 8]);
  gl_lds16(ag1, &As[0][c1 * 8]);
  gl_lds16(bg0, &Bs[0][c0 * 8]);
  gl_lds16(bg1, &Bs[0][c1 * 8]);
  CFENCE();

  int s = 0;
  for (int it = 0; it < NIT; ++it, s ^= 1) {
    if (it + 1 < NIT) {
      int k1 = (it + 1) * 32;
      gl_lds16(ag0 + k1, &As[s ^ 1][c0 * 8]);
      gl_lds16(ag1 + k1, &As[s ^ 1][c1 * 8]);
      gl_lds16(bg0 + k1, &Bs[s ^ 1][c0 * 8]);
      gl_lds16(bg1 + k1, &Bs[s ^ 1][c1 * 8]);
      CFENCE();
      asm volatile("s_waitcnt vmcnt(4)" ::: "memory");
    } else {
      asm volatile("s_waitcnt vmcnt(0)" ::: "memory");
    }
    __builtin_amdgcn_s_barrier();
    CFENCE();
    short8 af[4], bf[4];
#pragma unroll
    for (int i = 0; i < 4; i++) af[i] = *(const short8*)&As[s][offA[i]];
#pragma unroll
    for (int i = 0; i < 4; i++) bf[i] = *(const short8*)&Bs[s][offB[i]];
    __builtin_amdgcn_s_setprio(1);
#pragma unroll
    for (int mi = 0; mi < 4; mi++)
#pragma unroll
      for (int ni = 0; ni < 4; ni++)
        acc[mi][ni] = __builtin_amdgcn_mfma_f32_16x16x32_bf16(af[mi], bf[ni], acc[mi][ni], 0, 0, 0);
    __builtin_amdgcn_s_setprio(0);
    __builtin_amdgcn_s_barrier();
    CFENCE();
  }

  // ---- epilogue: repack through LDS (As region, 32x128 fp32 = 16 KB) so global
  // stores are row-contiguous float4 instead of 16 scalar dwords/thread ----
  __syncthreads();     // full drain before As reuse
  float* FB = (float*)&As[0][0];
  float* yb = Yp + (size_t)ks * SLOTS * DMODEL;
  float bv[4];
#pragma unroll
  for (int ni = 0; ni < 4; ni++)
    bv[ni] = (ks == 0) ? b2[e * DMODEL + nt * 128 + wn * 64 + ni * 16 + (lane & 15)] : 0.f;
  const int rq = (lane >> 4) * 4;
#pragma unroll
  for (int mi = 0; mi < 4; mi++) {
#pragma unroll
    for (int ni = 0; ni < 4; ni++)
#pragma unroll
      for (int r = 0; r < 4; r++)
        FB[(wm * 16 + rq + r) * 128 + wn * 64 + ni * 16 + (lane & 15)] = acc[mi][ni][r] + bv[ni];
    __syncthreads();
#pragma unroll
    for (int j = 0; j < 4; j++) {
      int fid = j * 256 + tid;               // 1024 float4 = 32 rows x 128 floats
      int lr = fid >> 5, c4 = fid & 31;
      int grow = mt * 128 + (lr >> 4) * 64 + mi * 16 + (lr & 15);
      if (grow < cnt)
        *(float4*)&yb[(size_t)(bse + grow) * DMODEL + nt * 128 + c4 * 4] =
            *(const float4*)&FB[lr * 128 + c4 * 4];
    }
    __syncthreads();   // before next mi overwrites FB
  }
}

// ---------------- combine: out[t] = w0*(Yp0[s0]+Yp1[s0]) + w1*(Yp0[s1]+Yp1[s1]) ----------------
__global__ void combine_kernel(const float* __restrict__ Yp, const int* __restrict__ tok_map,
                               const float* __restrict__ tok_w, float* __restrict__ out) {
  const int t = blockIdx.x;
  const int s0 = tok_map[2 * t], s1 = tok_map[2 * t + 1];
  const float w0 = tok_w[2 * t], w1 = tok_w[2 * t + 1];
  const int i = threadIdx.x * 4;
  const float* y0a = Yp + (size_t)s0 * DMODEL;
  const float* y0b = y0a + (size_t)SLOTS * DMODEL;
  const float* y1a = Yp + (size_t)s1 * DMODEL;
  const float* y1b = y1a + (size_t)SLOTS * DMODEL;
  float4 a = *(const float4*)&y0a[i];
  float4 b = *(const float4*)&y0b[i];
  float4 c = *(const float4*)&y1a[i];
  float4 d = *(const float4*)&y1b[i];
  float4 r;
  r.x = w0 * (a.x + b.x) + w1 * (c.x + d.x);
  r.y = w0 * (a.y + b.y) + w1 * (c.y + d.y);
  r.z = w0 * (a.z + b.z) + w1 * (c.z + d.z);
  r.w = w0 * (a.w + b.w) + w1 * (c.w + d.w);
  *(float4*)&out[(size_t)t * DMODEL + i] = r;
}

extern "C" void kernel_launch(void* const* d_in, const int* in_sizes, int n_in,
                              void* d_out, int out_size, void* d_ws, size_t ws_size,
                              hipStream_t stream) {
  const float* x  = (const float*)d_in[0];
  const float* Wg = (const float*)d_in[1];
  const float* bg = (const float*)d_in[2];
  const float* W1 = (const float*)d_in[3];
  const float* b1 = (const float*)d_in[4];
  const float* W2 = (const float*)d_in[5];
  const float* b2 = (const float*)d_in[6];
  float* out = (float*)d_out;

  char* p = (char*)d_ws;
  int*   counts   = (int*)p;   p += 256;
  int*   base     = (int*)p;   p += 256;
  int*   tstart   = (int*)p;   p += 256;
  int*   slot_tok = (int*)p;   p += (size_t)NEXP * TOKENS * 4;
  float* slot_w   = (float*)p; p += (size_t)NEXP * TOKENS * 4;
  int*   tok_map  = (int*)p;   p += (size_t)SLOTS * 4;
  float* tok_w    = (float*)p; p += (size_t)SLOTS * 4;
  u16*   xb       = (u16*)p;   p += (size_t)TOKENS * DMODEL * 2;
  u16*   w1t      = (u16*)p;   p += (size_t)NEXP * DMODEL * DFF * 2;   // 64 MB
  u16*   w2t      = (u16*)p;   p += (size_t)NEXP * DMODEL * DFF * 2;   // 64 MB
  u16*   H        = (u16*)p;   p += (size_t)SLOTS * DFF * 2;           // 64 MB
  // Yp (2 x 32 MB fp32 partials) ALIASES w1t: dead after gemm1; gemm2 ordered after.
  float* Yp = (float*)w1t;

  (void)hipMemsetAsync(counts, 0, 256, stream);

  transpose_cvt_kernel<<<dim3(1024, 1, 16), 256, 0, stream>>>(W1, w1t, W2, w2t);
  gate_kernel<<<TOKENS, 64, 0, stream>>>(x, Wg, bg, counts, slot_tok, slot_w, xb);
  prefix_kernel<<<1, 64, 0, stream>>>(counts, base, tstart);
  build_map_kernel<<<dim3(TOKENS / 256, NEXP), 256, 0, stream>>>(
      counts, base, slot_tok, slot_w, tok_map, tok_w);
  gemm1_kernel<<<MAXT * 32, 256, 0, stream>>>(
      xb, w1t, b1, slot_tok, counts, base, tstart, H);
  gemm2_kernel<<<MAXT * 16, 256, 0, stream>>>(
      H, w2t, b2, counts, base, tstart, Yp);
  combine_kernel<<<TOKENS, 256, 0, stream>>>(Yp, tok_map, tok_w, out);
}

// Round 4
// 635.849 us; speedup vs baseline: 1.0479x; 1.0092x over previous
//
#include <hip/hip_runtime.h>
#include <cstdint>

#define TOKENS 4096
#define DMODEL 1024
#define DFF    4096
#define NEXP   8
#define SLOTS  (2 * TOKENS)   // 8192 (token,expert) pairs
#define KS2    2              // K-split for gemm2 (4096 -> 2 x 2048), partial Y buffers
#define MAXT   71             // max total m-tiles: floor(8192/128) + 7

typedef unsigned short u16;
typedef __attribute__((ext_vector_type(8))) short short8;   // 8 bf16 (4 VGPRs)
typedef __attribute__((ext_vector_type(4))) float f32x4;

__device__ __forceinline__ u16 f2bf(float f) {
  union { float f; uint32_t u; } c; c.f = f;
  uint32_t u = c.u;
  u += 0x7fffu + ((u >> 16) & 1u);   // round-to-nearest-even
  return (u16)(u >> 16);
}

__device__ __forceinline__ void gl_lds16(const void* g, void* l) {
  __builtin_amdgcn_global_load_lds((__attribute__((address_space(1))) void*)(g),
                                   (__attribute__((address_space(3))) void*)(l),
                                   16, 0, 0);
}

#define CFENCE() asm volatile("" ::: "memory")

// ------- W [E][K][N] fp32 -> [E][N][K] bf16 (K-major for MFMA operands) -------
__global__ void transpose_cvt_kernel(const float* __restrict__ W1, u16* __restrict__ w1t,
                                     const float* __restrict__ W2, u16* __restrict__ w2t) {
  const int z = blockIdx.z;
  int K, N; const float* ip; u16* op;
  if (z < 8) { K = DMODEL; N = DFF;    ip = W1 + (size_t)z * K * N;       op = w1t + (size_t)z * K * N; }
  else       { K = DFF;    N = DMODEL; ip = W2 + (size_t)(z - 8) * K * N; op = w2t + (size_t)(z - 8) * K * N; }
  const int ntn = N >> 6;
  const int nt = (blockIdx.x & (ntn - 1)) << 6;
  const int kt = (blockIdx.x / ntn) << 6;

  __shared__ float tile[64][65];
  const int tid = threadIdx.x;
#pragma unroll
  for (int i = 0; i < 4; i++) {
    int idx = tid + i * 256;
    int r = idx >> 4, cg = idx & 15;
    float4 v = *(const float4*)&ip[(size_t)(kt + r) * N + nt + cg * 4];
    tile[r][cg * 4 + 0] = v.x;
    tile[r][cg * 4 + 1] = v.y;
    tile[r][cg * 4 + 2] = v.z;
    tile[r][cg * 4 + 3] = v.w;
  }
  __syncthreads();
#pragma unroll
  for (int i = 0; i < 2; i++) {
    int rr = (tid >> 3) + i * 32;
    int kc = tid & 7;
    union { u16 u[8]; uint4 v; } r8;
#pragma unroll
    for (int j = 0; j < 8; j++) r8.u[j] = f2bf(tile[kc * 8 + j][rr]);
    *(uint4*)&op[(size_t)(nt + rr) * K + kt + kc * 8] = r8.v;
  }
}

// ---------------- gating (+ fused x fp32->bf16): one wave per token ----------------
__global__ void gate_kernel(const float* __restrict__ x, const float* __restrict__ Wg,
                            const float* __restrict__ bg, int* __restrict__ counts,
                            int* __restrict__ slot_tok, float* __restrict__ slot_w,
                            u16* __restrict__ xb) {
  const int t = blockIdx.x;
  const int lane = threadIdx.x;
  const float* xr = x + (size_t)t * DMODEL;
  float acc[NEXP];
#pragma unroll
  for (int e = 0; e < NEXP; e++) acc[e] = 0.f;
#pragma unroll
  for (int i = 0; i < 4; i++) {
    int k = (lane + i * 64) * 4;
    float4 xv = *(const float4*)&xr[k];
    union { u16 u[4]; uint2 v; } q;
    q.u[0] = f2bf(xv.x); q.u[1] = f2bf(xv.y); q.u[2] = f2bf(xv.z); q.u[3] = f2bf(xv.w);
    *(uint2*)&xb[(size_t)t * DMODEL + k] = q.v;
    const float* wr = &Wg[k * NEXP];
    float xa[4] = {xv.x, xv.y, xv.z, xv.w};
#pragma unroll
    for (int j = 0; j < 4; j++)
#pragma unroll
      for (int e = 0; e < NEXP; e++) acc[e] += xa[j] * wr[j * NEXP + e];
  }
#pragma unroll
  for (int off = 32; off >= 1; off >>= 1)
#pragma unroll
    for (int e = 0; e < NEXP; e++) acc[e] += __shfl_xor(acc[e], off);
  if (lane == 0) {
#pragma unroll
    for (int e = 0; e < NEXP; e++) acc[e] += bg[e];
    int i0 = 0; float v0 = acc[0];
#pragma unroll
    for (int e = 1; e < NEXP; e++) if (acc[e] > v0) { v0 = acc[e]; i0 = e; }
    int i1 = -1; float v1 = -3.0e38f;
#pragma unroll
    for (int e = 0; e < NEXP; e++) if (e != i0 && acc[e] > v1) { v1 = acc[e]; i1 = e; }
    float ex = __expf(v1 - v0);
    float inv = 1.0f / (1.0f + ex);
    int p0 = atomicAdd(&counts[i0], 1);
    slot_tok[i0 * TOKENS + p0] = t * 2;     slot_w[i0 * TOKENS + p0] = inv;
    int p1 = atomicAdd(&counts[i1], 1);
    slot_tok[i1 * TOKENS + p1] = t * 2 + 1; slot_w[i1 * TOKENS + p1] = ex * inv;
  }
}

// prefix over slots AND over m-tiles (compact GEMM work list)
__global__ void prefix_kernel(const int* __restrict__ counts, int* __restrict__ base,
                              int* __restrict__ tstart) {
  if (threadIdx.x == 0) {
    int s = 0, ts = 0;
    for (int e = 0; e < NEXP; e++) {
      base[e] = s; tstart[e] = ts;
      s += counts[e];
      ts += (counts[e] + 127) >> 7;
    }
    tstart[NEXP] = ts;
  }
}

// ---------------- token -> (global slot, weight) inverse map ----------------
__global__ void build_map_kernel(const int* __restrict__ counts, const int* __restrict__ base,
                                 const int* __restrict__ slot_tok, const float* __restrict__ slot_w,
                                 int* __restrict__ tok_map, float* __restrict__ tok_w) {
  int e = blockIdx.y;
  int p = blockIdx.x * 256 + threadIdx.x;
  if (p < counts[e]) {
    int t2 = slot_tok[e * TOKENS + p];
    tok_map[t2] = base[e] + p;
    tok_w[t2] = slot_w[e * TOKENS + p];
  }
}

// LDS bank-conflict swizzle for the 128x32-u16 staging tiles (64 B rows):
// LDS 16B-chunk (row r, chunk c) holds global chunk (r, c ^ ((r>>1)&3)).
__device__ __forceinline__ int swz_koff(int c) {           // staging thread c -> u16 offset
  return (((c & 3) ^ ((c >> 3) & 3)) * 8);
}
__device__ __forceinline__ int swz_read(int R, int chunk) { // row R, wanted chunk -> u16 offset
  return R * 32 + ((chunk ^ ((R >> 1) & 3)) * 8);
}

// ============ 128x128 / BK=32 / 4-wave GEMMs, 3-buffer / 2-ahead / 1-barrier schedule ============
// Per K-step: [vmcnt(4) -> s_barrier -> issue stage(t+2) -> ds_read buf t%3 -> MFMA].
// Invariants: at the wait a wave has stages t,t+1 outstanding (8 loads) -> vmcnt(4) retires
// stage(t); barrier makes it collective. stage(t+2) overwrites buf (t-1)%3, whose readers all
// passed barrier(t) (reads consumed by their MFMAs before arrival) -> no end-of-step barrier
// needed. Stage(t) gets ~2 K-steps of latency cover; in-flight never <4 until the final tile.

// ---------------- GEMM1: H[slot, :] = relu(Xgather @ W1t^T + b1), bf16 out ----------------
__global__ __launch_bounds__(256, 3) void gemm1_kernel(
    const u16* __restrict__ xb, const u16* __restrict__ w1t, const float* __restrict__ b1,
    const int* __restrict__ slot_tok, const int* __restrict__ counts,
    const int* __restrict__ base, const int* __restrict__ tstart, u16* __restrict__ H) {
  const int nwg = MAXT * 32;                    // 2272, %8==0
  const int bid = (int)blockIdx.x;
  const int wg = (bid & 7) * (nwg >> 3) + (bid >> 3);   // bijective XCD-chunk swizzle (T1)
  const int nt = wg & 31;
  const int trow = wg >> 5;
  if (trow >= tstart[NEXP]) return;
  int e = 0;
#pragma unroll
  for (int i = 1; i < NEXP; i++) if (trow >= tstart[i]) e = i;
  const int mt = trow - tstart[e];
  const int cnt = counts[e];
  const int bse = base[e];
  const int tid = threadIdx.x;
  const int lane = tid & 63, wave = tid >> 6;
  const int wm = wave & 1, wn = wave >> 1;

  // 48 KB flat LDS: A bufs [b*4096], B bufs [12288 + b*4096], b in {0,1,2} (each 128x32 u16).
  // Epilogue reuses the first 16384 u16 as a 128x128 bf16 tile.
  __shared__ __align__(16) u16 SM[24576];

  const int c0 = tid, c1 = tid + 256;           // each: row=c>>2, kchunk=c&3
  const int ar0 = mt * 128 + (c0 >> 2), ar1 = mt * 128 + (c1 >> 2);
  const int t0 = (ar0 < cnt) ? (slot_tok[e * TOKENS + ar0] >> 1) : 0;
  const int t1 = (ar1 < cnt) ? (slot_tok[e * TOKENS + ar1] >> 1) : 0;
  const u16* ag0 = xb + (size_t)t0 * DMODEL + swz_koff(c0);
  const u16* ag1 = xb + (size_t)t1 * DMODEL + swz_koff(c1);
  const u16* wb  = w1t + (size_t)e * DFF * DMODEL;
  const u16* bg0 = wb + (size_t)(nt * 128 + (c0 >> 2)) * DMODEL + swz_koff(c0);
  const u16* bg1 = wb + (size_t)(nt * 128 + (c1 >> 2)) * DMODEL + swz_koff(c1);

#define G1_STAGE(b, ko) do { \
    gl_lds16(ag0 + (ko), &SM[(b) * 4096 + c0 * 8]); \
    gl_lds16(ag1 + (ko), &SM[(b) * 4096 + c1 * 8]); \
    gl_lds16(bg0 + (ko), &SM[12288 + (b) * 4096 + c0 * 8]); \
    gl_lds16(bg1 + (ko), &SM[12288 + (b) * 4096 + c1 * 8]); } while (0)

  f32x4 acc[4][4] = {};
  const int mr = wm * 64 + (lane & 15);
  const int nr = wn * 64 + (lane & 15);
  const int ch = lane >> 4;                     // wanted 16B k-chunk
  const int NIT = DMODEL / 32;                  // 32

  // per-lane swizzled read offsets (loop-invariant; only buffer base varies)
  int offA[4], offB[4];
#pragma unroll
  for (int i = 0; i < 4; i++) {
    offA[i] = swz_read(mr + i * 16, ch);
    offB[i] = 12288 + swz_read(nr + i * 16, ch);
  }

  // prologue: stage tiles 0 and 1 (8 loads outstanding)
  G1_STAGE(0, 0);
  CFENCE();
  G1_STAGE(1, 32);
  CFENCE();

  int b0 = 0, bs = 2;
  for (int it = 0; it < NIT; ++it) {
    if (it + 1 < NIT) {
      asm volatile("s_waitcnt vmcnt(4)" ::: "memory");   // stage(it) landed; stage(it+1) in flight
    } else {
      asm volatile("s_waitcnt vmcnt(0)" ::: "memory");   // final tile
    }
    __builtin_amdgcn_s_barrier();
    CFENCE();
    if (it + 2 < NIT) {
      G1_STAGE(bs, (it + 2) * 32);   // overwrites buf (it-1)%3 — safe post-barrier
      CFENCE();
    }
    const int ab = b0 * 4096;
    short8 af[4], bf[4];
#pragma unroll
    for (int i = 0; i < 4; i++) af[i] = *(const short8*)&SM[ab + offA[i]];
#pragma unroll
    for (int i = 0; i < 4; i++) bf[i] = *(const short8*)&SM[ab + offB[i]];
    __builtin_amdgcn_s_setprio(1);
#pragma unroll
    for (int mi = 0; mi < 4; mi++)
#pragma unroll
      for (int ni = 0; ni < 4; ni++)
        acc[mi][ni] = __builtin_amdgcn_mfma_f32_16x16x32_bf16(af[mi], bf[ni], acc[mi][ni], 0, 0, 0);
    __builtin_amdgcn_s_setprio(0);
    b0 = (b0 == 2) ? 0 : b0 + 1;
    bs = (bs == 2) ? 0 : bs + 1;
  }
#undef G1_STAGE

  // ---- epilogue: bias+relu+cvt into LDS tile, then coalesced b128 stores ----
  __syncthreads();   // full drain + all waves done with K-loop reads before SM reuse
  const int rq = (lane >> 4) * 4;
#pragma unroll
  for (int ni = 0; ni < 4; ni++) {
    const int col = wn * 64 + ni * 16 + (lane & 15);
    const float bv = b1[e * DFF + nt * 128 + col];
#pragma unroll
    for (int mi = 0; mi < 4; mi++)
#pragma unroll
      for (int r = 0; r < 4; r++) {
        int row = wm * 64 + mi * 16 + rq + r;
        float v = acc[mi][ni][r] + bv;
        SM[row * 128 + col] = f2bf(v > 0.f ? v : 0.f);
      }
  }
  __syncthreads();
#pragma unroll
  for (int rep = 0; rep < 8; rep++) {
    int idx = rep * 256 + tid;          // 2048 = 128 rows x 16 chunks
    int r = idx >> 4, chk = idx & 15;
    int grow = mt * 128 + r;
    if (grow < cnt)
      *(uint4*)&H[(size_t)(bse + grow) * DFF + nt * 128 + chk * 8] =
          *(const uint4*)&SM[r * 128 + chk * 8];
  }
}

// ------- GEMM2 (K-split x2, no atomics): Yp[ks][slot, :] = H @ W2t^T (+ b2 on ks=0) -------
__global__ __launch_bounds__(256, 3) void gemm2_kernel(
    const u16* __restrict__ H, const u16* __restrict__ w2t, const float* __restrict__ b2,
    const int* __restrict__ counts, const int* __restrict__ base,
    const int* __restrict__ tstart, float* __restrict__ Yp) {
  const int nwg = MAXT * 16;                    // 1136, %8==0
  const int bid = (int)blockIdx.x;
  const int wg = (bid & 7) * (nwg >> 3) + (bid >> 3);
  const int nks = wg & 15;
  const int nt = nks & 7, ks = nks >> 3;
  const int trow = wg >> 4;
  if (trow >= tstart[NEXP]) return;
  int e = 0;
#pragma unroll
  for (int i = 1; i < NEXP; i++) if (trow >= tstart[i]) e = i;
  const int mt = trow - tstart[e];
  const int cnt = counts[e];
  const int bse = base[e];
  const int kbeg = ks * (DFF / KS2);
  const int tid = threadIdx.x;
  const int lane = tid & 63, wave = tid >> 6;
  const int wm = wave & 1, wn = wave >> 1;

  // 48 KB flat LDS, same layout as gemm1; epilogue reuses first 16 KB as 32x128 f32.
  __shared__ __align__(16) u16 SM[24576];

  const int c0 = tid, c1 = tid + 256;
  const int ar0 = mt * 128 + (c0 >> 2), ar1 = mt * 128 + (c1 >> 2);
  const int hr0 = bse + ((ar0 < cnt) ? ar0 : 0);
  const int hr1 = bse + ((ar1 < cnt) ? ar1 : 0);
  const u16* ag0 = H + (size_t)hr0 * DFF + kbeg + swz_koff(c0);
  const u16* ag1 = H + (size_t)hr1 * DFF + kbeg + swz_koff(c1);
  const u16* wb  = w2t + (size_t)e * DMODEL * DFF;
  const u16* bg0 = wb + (size_t)(nt * 128 + (c0 >> 2)) * DFF + kbeg + swz_koff(c0);
  const u16* bg1 = wb + (size_t)(nt * 128 + (c1 >> 2)) * DFF + kbeg + swz_koff(c1);

#define G2_STAGE(b, ko) do { \
    gl_lds16(ag0 + (ko), &SM[(b) * 4096 + c0 * 8]); \
    gl_lds16(ag1 + (ko), &SM[(b) * 4096 + c1 * 8]); \
    gl_lds16(bg0 + (ko), &SM[12288 + (b) * 4096 + c0 * 8]); \
    gl_lds16(bg1 + (ko), &SM[12288 + (b) * 4096 + c1 * 8]); } while (0)

  f32x4 acc[4][4] = {};
  const int mr = wm * 64 + (lane & 15);
  const int nr = wn * 64 + (lane & 15);
  const int ch = lane >> 4;
  const int NIT = (DFF / KS2) / 32;             // 64

  int offA[4], offB[4];
#pragma unroll
  for (int i = 0; i < 4; i++) {
    offA[i] = swz_read(mr + i * 16, ch);
    offB[i] = 12288 + swz_read(nr + i * 16, ch);
  }

  G2_STAGE(0, 0);
  CFENCE();
  G2_STAGE(1, 32);
  CFENCE();

  int b0 = 0, bs = 2;
  for (int it = 0; it < NIT; ++it) {
    if (it + 1 < NIT) {
      asm volatile("s_waitcnt vmcnt(4)" ::: "memory");
    } else {
      asm volatile("s_waitcnt vmcnt(0)" ::: "memory");
    }
    __builtin_amdgcn_s_barrier();
    CFENCE();
    if (it + 2 < NIT) {
      G2_STAGE(bs, (it + 2) * 32);
      CFENCE();
    }
    const int ab = b0 * 4096;
    short8 af[4], bf[4];
#pragma unroll
    for (int i = 0; i < 4; i++) af[i] = *(const short8*)&SM[ab + offA[i]];
#pragma unroll
    for (int i = 0; i < 4; i++) bf[i] = *(const short8*)&SM[ab + offB[i]];
    __builtin_amdgcn_s_setprio(1);
#pragma unroll
    for (int mi = 0; mi < 4; mi++)
#pragma unroll
      for (int ni = 0; ni < 4; ni++)
        acc[mi][ni] = __builtin_amdgcn_mfma_f32_16x16x32_bf16(af[mi], bf[ni], acc[mi][ni], 0, 0, 0);
    __builtin_amdgcn_s_setprio(0);
    b0 = (b0 == 2) ? 0 : b0 + 1;
    bs = (bs == 2) ? 0 : bs + 1;
  }
#undef G2_STAGE

  // ---- epilogue: repack through LDS (first 16 KB as 32x128 fp32) so global
  // stores are row-contiguous float4 instead of 16 scalar dwords/thread ----
  __syncthreads();     // full drain before SM reuse
  float* FB = (float*)&SM[0];
  float* yb = Yp + (size_t)ks * SLOTS * DMODEL;
  float bv[4];
#pragma unroll
  for (int ni = 0; ni < 4; ni++)
    bv[ni] = (ks == 0) ? b2[e * DMODEL + nt * 128 + wn * 64 + ni * 16 + (lane & 15)] : 0.f;
  const int rq = (lane >> 4) * 4;
#pragma unroll
  for (int mi = 0; mi < 4; mi++) {
#pragma unroll
    for (int ni = 0; ni < 4; ni++)
#pragma unroll
      for (int r = 0; r < 4; r++)
        FB[(wm * 16 + rq + r) * 128 + wn * 64 + ni * 16 + (lane & 15)] = acc[mi][ni][r] + bv[ni];
    __syncthreads();
#pragma unroll
    for (int j = 0; j < 4; j++) {
      int fid = j * 256 + tid;               // 1024 float4 = 32 rows x 128 floats
      int lr = fid >> 5, c4 = fid & 31;
      int grow = mt * 128 + (lr >> 4) * 64 + mi * 16 + (lr & 15);
      if (grow < cnt)
        *(float4*)&yb[(size_t)(bse + grow) * DMODEL + nt * 128 + c4 * 4] =
            *(const float4*)&FB[lr * 128 + c4 * 4];
    }
    __syncthreads();   // before next mi overwrites FB
  }
}

// ---------------- combine: out[t] = w0*(Yp0[s0]+Yp1[s0]) + w1*(Yp0[s1]+Yp1[s1]) ----------------
__global__ void combine_kernel(const float* __restrict__ Yp, const int* __restrict__ tok_map,
                               const float* __restrict__ tok_w, float* __restrict__ out) {
  const int t = blockIdx.x;
  const int s0 = tok_map[2 * t], s1 = tok_map[2 * t + 1];
  const float w0 = tok_w[2 * t], w1 = tok_w[2 * t + 1];
  const int i = threadIdx.x * 4;
  const float* y0a = Yp + (size_t)s0 * DMODEL;
  const float* y0b = y0a + (size_t)SLOTS * DMODEL;
  const float* y1a = Yp + (size_t)s1 * DMODEL;
  const float* y1b = y1a + (size_t)SLOTS * DMODEL;
  float4 a = *(const float4*)&y0a[i];
  float4 b = *(const float4*)&y0b[i];
  float4 c = *(const float4*)&y1a[i];
  float4 d = *(const float4*)&y1b[i];
  float4 r;
  r.x = w0 * (a.x + b.x) + w1 * (c.x + d.x);
  r.y = w0 * (a.y + b.y) + w1 * (c.y + d.y);
  r.z = w0 * (a.z + b.z) + w1 * (c.z + d.z);
  r.w = w0 * (a.w + b.w) + w1 * (c.w + d.w);
  *(float4*)&out[(size_t)t * DMODEL + i] = r;
}

extern "C" void kernel_launch(void* const* d_in, const int* in_sizes, int n_in,
                              void* d_out, int out_size, void* d_ws, size_t ws_size,
                              hipStream_t stream) {
  const float* x  = (const float*)d_in[0];
  const float* Wg = (const float*)d_in[1];
  const float* bg = (const float*)d_in[2];
  const float* W1 = (const float*)d_in[3];
  const float* b1 = (const float*)d_in[4];
  const float* W2 = (const float*)d_in[5];
  const float* b2 = (const float*)d_in[6];
  float* out = (float*)d_out;

  char* p = (char*)d_ws;
  int*   counts   = (int*)p;   p += 256;
  int*   base     = (int*)p;   p += 256;
  int*   tstart   = (int*)p;   p += 256;
  int*   slot_tok = (int*)p;   p += (size_t)NEXP * TOKENS * 4;
  float* slot_w   = (float*)p; p += (size_t)NEXP * TOKENS * 4;
  int*   tok_map  = (int*)p;   p += (size_t)SLOTS * 4;
  float* tok_w    = (float*)p; p += (size_t)SLOTS * 4;
  u16*   xb       = (u16*)p;   p += (size_t)TOKENS * DMODEL * 2;
  u16*   w1t      = (u16*)p;   p += (size_t)NEXP * DMODEL * DFF * 2;   // 64 MB
  u16*   w2t      = (u16*)p;   p += (size_t)NEXP * DMODEL * DFF * 2;   // 64 MB
  u16*   H        = (u16*)p;   p += (size_t)SLOTS * DFF * 2;           // 64 MB
  // Yp (2 x 32 MB fp32 partials) ALIASES w1t: dead after gemm1; gemm2 ordered after.
  float* Yp = (float*)w1t;

  (void)hipMemsetAsync(counts, 0, 256, stream);

  transpose_cvt_kernel<<<dim3(1024, 1, 16), 256, 0, stream>>>(W1, w1t, W2, w2t);
  gate_kernel<<<TOKENS, 64, 0, stream>>>(x, Wg, bg, counts, slot_tok, slot_w, xb);
  prefix_kernel<<<1, 64, 0, stream>>>(counts, base, tstart);
  build_map_kernel<<<dim3(TOKENS / 256, NEXP), 256, 0, stream>>>(
      counts, base, slot_tok, slot_w, tok_map, tok_w);
  gemm1_kernel<<<MAXT * 32, 256, 0, stream>>>(
      xb, w1t, b1, slot_tok, counts, base, tstart, H);
  gemm2_kernel<<<MAXT * 16, 256, 0, stream>>>(
      H, w2t, b2, counts, base, tstart, Yp);
  combine_kernel<<<TOKENS, 256, 0, stream>>>(Yp, tok_map, tok_w, out);
}